// Round 5
// baseline (543.352 us; speedup 1.0000x reference)
//
#include <hip/hip_runtime.h>
#include <hip/hip_bf16.h>

#define N_NODES 100000
#define NB 784   // buckets of 128 nodes: 784*128 = 100352 >= N_NODES
#define NPAD 100352
#define BSH 7
#define BMASK 127
#define CAP 4096  // static per-bucket capacity (mean 2040 -> safe)
#define MSTRIDE 36 // u32 stride of an LDS mean row (32 payload + 4 pad)

typedef float v2f __attribute__((ext_vector_type(2)));

__device__ inline void fma4(float a, const float4& w, float4& c) {
  c.x = fmaf(a, w.x, c.x);
  c.y = fmaf(a, w.y, c.y);
  c.z = fmaf(a, w.z, c.z);
  c.w = fmaf(a, w.w, c.w);
}
__device__ inline unsigned short f2bf(float f) {  // RNE f32->bf16
  unsigned u = __float_as_uint(f);
  u += 0x7fffu + ((u >> 16) & 1u);
  return (unsigned short)(u >> 16);
}
__device__ inline unsigned pack2bf(float a, float b) {
  return (unsigned)f2bf(a) | ((unsigned)f2bf(b) << 16);
}
__device__ inline unsigned packfp8x4(float a, float b, float c, float d) {
  int pk = __builtin_amdgcn_cvt_pk_fp8_f32(a, b, 0, false);
  pk = __builtin_amdgcn_cvt_pk_fp8_f32(c, d, pk, true);
  return (unsigned)pk;
}
// relu(bf16(m) + bf16(s)) for 4 packed bf16 elements (bit-identical f32 math)
__device__ inline float4 relu_mix(uint2 m, uint2 s) {
  float4 v;
  v.x = fmaxf(__uint_as_float(m.x << 16) + __uint_as_float(s.x << 16), 0.f);
  v.y = fmaxf(__uint_as_float(m.x & 0xffff0000u) +
                  __uint_as_float(s.x & 0xffff0000u), 0.f);
  v.z = fmaxf(__uint_as_float(m.y << 16) + __uint_as_float(s.y << 16), 0.f);
  v.w = fmaxf(__uint_as_float(m.y & 0xffff0000u) +
                  __uint_as_float(s.y & 0xffff0000u), 0.f);
  return v;
}

#define GB1 1563   // ceil(100000/64); also 1563*1024 = 1,600,512 >= E
#define SEPB 1024  // edges scattered per block (4/thread)

// ---------------------------------------------------------------------------
// R18 fusedB: HOMOGENEOUS blocks. Every block first scatters 1024 edges via
// per-edge device-scope atomicAdd on bcur[bucket] (no LDS, no barriers, no
// rank phases -> no serial chain; ~6k independent {ld,ld,atomic,st} chains
// in flight chip-wide hide under gemm1 VALU), then runs its 64-row layer-1
// dual-GEMM tile. R4 counters showed the old 196-block rank-scatter was a
// 57us latency chain at 15% HBM / 23% VALU; write amplification was NOT the
// binding constraint, chain length was.
// ---------------------------------------------------------------------------
__global__ __launch_bounds__(256) void fusedB_k(
    const int* __restrict__ src, const int* __restrict__ dst,
    unsigned* __restrict__ bcur, unsigned* __restrict__ ep,
    const float* __restrict__ x, const float* __restrict__ W1n,
    const float* __restrict__ W1s, const float* __restrict__ b1,
    unsigned* __restrict__ xnb8, unsigned short* __restrict__ xsb,
    int E, int M) {
  __shared__ __align__(16) float smem[8192];  // 32768 B
  float* Wn = smem;
  float* Ws = smem + 4096;
  const int tid = threadIdx.x;
  const int bid = blockIdx.x;

  // ---- scatter prologue: 4 edges/thread, fully independent chains ----
  const int ebase = bid * SEPB;
  int es[4], ed[4];
  bool ev[4];
#pragma unroll
  for (int it = 0; it < 4; ++it) {
    int e = ebase + it * 256 + tid;
    ev[it] = (e < E);
    if (ev[it]) {
      es[it] = src[e];
      ed[it] = dst[e];
    }
  }

  // weight staging can issue while edge loads are in flight
  for (int i = tid; i < 1024; i += 256) {
    ((float4*)Wn)[i] = ((const float4*)W1n)[i];
    ((float4*)Ws)[i] = ((const float4*)W1s)[i];
  }

#pragma unroll
  for (int it = 0; it < 4; ++it) {
    if (ev[it]) {
      unsigned b = ((unsigned)ed[it]) >> BSH;
      unsigned r = atomicAdd(&bcur[b], 1u);
      ep[(size_t)b * CAP + r] =
          (((unsigned)es[it]) << BSH) | (((unsigned)ed[it]) & BMASK);
    }
  }

  // ---- gemm1 body ----
  const int row0 = bid * 64;
  const int tx = tid & 15;
  const int ty = tid >> 4;
  const int arow = ty * 4;

  // clamped per-row global pointers (A reads are 16-lane broadcasts via L1)
  const float* xr[4];
#pragma unroll
  for (int r = 0; r < 4; ++r) {
    long long gr = row0 + arow + r;
    if (gr >= M) gr = M - 1;
    xr[r] = x + gr * 64;
  }

  float4 an[4], as[4];
#pragma unroll
  for (int r = 0; r < 4; ++r) {
    an[r] = make_float4(0.f, 0.f, 0.f, 0.f);
    as[r] = make_float4(0.f, 0.f, 0.f, 0.f);
  }
  __syncthreads();

#pragma unroll 2
  for (int k4 = 0; k4 < 16; ++k4) {
    float4 a[4];
#pragma unroll
    for (int r = 0; r < 4; ++r) a[r] = *(const float4*)(xr[r] + 4 * k4);
    float4 wn0 = *(const float4*)&Wn[(4 * k4 + 0) * 64 + 4 * tx];
    float4 wn1 = *(const float4*)&Wn[(4 * k4 + 1) * 64 + 4 * tx];
    float4 wn2 = *(const float4*)&Wn[(4 * k4 + 2) * 64 + 4 * tx];
    float4 wn3 = *(const float4*)&Wn[(4 * k4 + 3) * 64 + 4 * tx];
    float4 ws0 = *(const float4*)&Ws[(4 * k4 + 0) * 64 + 4 * tx];
    float4 ws1 = *(const float4*)&Ws[(4 * k4 + 1) * 64 + 4 * tx];
    float4 ws2 = *(const float4*)&Ws[(4 * k4 + 2) * 64 + 4 * tx];
    float4 ws3 = *(const float4*)&Ws[(4 * k4 + 3) * 64 + 4 * tx];
#pragma unroll
    for (int r = 0; r < 4; ++r) {
      fma4(a[r].x, wn0, an[r]);
      fma4(a[r].y, wn1, an[r]);
      fma4(a[r].z, wn2, an[r]);
      fma4(a[r].w, wn3, an[r]);
      fma4(a[r].x, ws0, as[r]);
      fma4(a[r].y, ws1, as[r]);
      fma4(a[r].z, ws2, as[r]);
      fma4(a[r].w, ws3, as[r]);
    }
  }

  const float4 bv = *(const float4*)&b1[4 * tx];
#pragma unroll
  for (int r = 0; r < 4; ++r) {
    int row = row0 + arow + r;
    if (row < M) {
      ushort4 ps;
      ps.x = f2bf(as[r].x + bv.x);
      ps.y = f2bf(as[r].y + bv.y);
      ps.z = f2bf(as[r].z + bv.z);
      ps.w = f2bf(as[r].w + bv.w);
      *(ushort4*)&xsb[(long long)row * 64 + 4 * tx] = ps;
      xnb8[(size_t)row * 16 + tx] =
          packfp8x4(an[r].x, an[r].y, an[r].z, an[r].w);
    }
  }
}

// ---------------------------------------------------------------------------
// bsort: per-bucket counting sort by dst&127 -> per-node contiguous src runs.
// ---------------------------------------------------------------------------
__global__ __launch_bounds__(256) void bsort_k(const unsigned* __restrict__ ep,
                                               const unsigned* __restrict__ bcur,
                                               int* __restrict__ ssrc,
                                               uint2* __restrict__ rows2) {
  __shared__ unsigned cnt[128];
  __shared__ unsigned sc[128];
  const int tid = threadIdx.x;
  const int b = blockIdx.x;
  const unsigned cntb = bcur[b];
  const unsigned beg = (unsigned)(b * CAP);
  if (tid < 128) cnt[tid] = 0;
  __syncthreads();
  for (unsigned j = tid; j < cntb; j += 256)
    atomicAdd(&cnt[ep[(size_t)beg + j] & BMASK], 1u);
  __syncthreads();
  unsigned v = (tid < 128) ? cnt[tid] : 0u;
  if (tid < 128) sc[tid] = v;
  __syncthreads();
  for (int off = 1; off < 128; off <<= 1) {
    unsigned t = (tid < 128 && tid >= off) ? sc[tid - off] : 0u;
    __syncthreads();
    if (tid < 128) sc[tid] += t;
    __syncthreads();
  }
  if (tid < 128) {
    unsigned ex = sc[tid] - v;
    rows2[b * 128 + tid] = make_uint2(beg + ex, beg + ex + v);
    cnt[tid] = ex;
  }
  __syncthreads();
  for (unsigned j = tid; j < cntb; j += 256) {
    unsigned p = ep[(size_t)beg + j];
    unsigned r = atomicAdd(&cnt[p & BMASK], 1u);
    ssrc[(size_t)beg + r] = (int)(p >> BSH);
  }
}

// ---------------------------------------------------------------------------
// fgg: fused gather1 + gemm2 per 64 nodes (R15-proven). Gather phase computes
// mean_j fp8decode(xnb8[ssrc[j]]) -> bf16-packed rows in LDS (stride 36 u32);
// GEMM phase does hn(fp8)/hs = relu(mean+xs)@{W2n,W2s}+b2.
// ---------------------------------------------------------------------------
__global__ __launch_bounds__(256) void fgg_k(
    const uint4* __restrict__ valb4, const int* __restrict__ ssrc,
    const uint2* __restrict__ rows2, const unsigned short* __restrict__ xsb,
    const float* __restrict__ W2n, const float* __restrict__ W2s,
    const float* __restrict__ b2, unsigned* __restrict__ hnb8,
    float* __restrict__ hs, int M) {
  __shared__ float Wn[64 * 32];
  __shared__ float Ws[64 * 32];
  __shared__ unsigned mlds[64 * MSTRIDE];  // 9216 B
  const int tid = threadIdx.x;
  const int node0 = blockIdx.x * 64;

  for (int i = tid; i < 512; i += 256) {
    ((float4*)Wn)[i] = ((const float4*)W2n)[i];
    ((float4*)Ws)[i] = ((const float4*)W2s)[i];
  }

  // ---- gather phase: P=4 lanes per node, 16 cols each ----
  constexpr int P = 4;
  const int lrow = tid / P;            // 0..63
  const int node = node0 + lrow;       // < 100032 <= NPAD, rows2 always valid
  const int p = tid & 3;
  const uint2 be = rows2[node];
  const unsigned beg = be.x, end = be.y;  // deg-0 (incl node>=M) -> beg==end

  float acc[16];
#pragma unroll
  for (int q = 0; q < 16; ++q) acc[q] = 0.f;

  unsigned j = beg;
  for (; j + 8 <= end; j += 8) {
    int sn[8];
#pragma unroll
    for (int i = 0; i < 8; ++i) sn[i] = ssrc[j + i];
    uint4 u[8];
#pragma unroll
    for (int i = 0; i < 8; ++i) u[i] = valb4[(size_t)sn[i] * P + p];
#pragma unroll
    for (int i = 0; i < 8; ++i) {
      v2f f0 = __builtin_amdgcn_cvt_pk_f32_fp8((int)u[i].x, false);
      v2f f1 = __builtin_amdgcn_cvt_pk_f32_fp8((int)u[i].x, true);
      v2f f2 = __builtin_amdgcn_cvt_pk_f32_fp8((int)u[i].y, false);
      v2f f3 = __builtin_amdgcn_cvt_pk_f32_fp8((int)u[i].y, true);
      v2f f4 = __builtin_amdgcn_cvt_pk_f32_fp8((int)u[i].z, false);
      v2f f5 = __builtin_amdgcn_cvt_pk_f32_fp8((int)u[i].z, true);
      v2f f6 = __builtin_amdgcn_cvt_pk_f32_fp8((int)u[i].w, false);
      v2f f7 = __builtin_amdgcn_cvt_pk_f32_fp8((int)u[i].w, true);
      acc[0] += f0[0];  acc[1] += f0[1];
      acc[2] += f1[0];  acc[3] += f1[1];
      acc[4] += f2[0];  acc[5] += f2[1];
      acc[6] += f3[0];  acc[7] += f3[1];
      acc[8] += f4[0];  acc[9] += f4[1];
      acc[10] += f5[0]; acc[11] += f5[1];
      acc[12] += f6[0]; acc[13] += f6[1];
      acc[14] += f7[0]; acc[15] += f7[1];
    }
  }
  if (j < end) {
    const unsigned last = end - 1;
    int sn[8];
#pragma unroll
    for (int i = 0; i < 8; ++i) {
      unsigned jj = j + i;
      sn[i] = ssrc[jj < last ? jj : last];
    }
    uint4 u[8];
#pragma unroll
    for (int i = 0; i < 8; ++i) u[i] = valb4[(size_t)sn[i] * P + p];
#pragma unroll
    for (int i = 0; i < 8; ++i) {
      float w = ((j + i) < end) ? 1.f : 0.f;
      v2f f0 = __builtin_amdgcn_cvt_pk_f32_fp8((int)u[i].x, false);
      v2f f1 = __builtin_amdgcn_cvt_pk_f32_fp8((int)u[i].x, true);
      v2f f2 = __builtin_amdgcn_cvt_pk_f32_fp8((int)u[i].y, false);
      v2f f3 = __builtin_amdgcn_cvt_pk_f32_fp8((int)u[i].y, true);
      v2f f4 = __builtin_amdgcn_cvt_pk_f32_fp8((int)u[i].z, false);
      v2f f5 = __builtin_amdgcn_cvt_pk_f32_fp8((int)u[i].z, true);
      v2f f6 = __builtin_amdgcn_cvt_pk_f32_fp8((int)u[i].w, false);
      v2f f7 = __builtin_amdgcn_cvt_pk_f32_fp8((int)u[i].w, true);
      acc[0] = fmaf(w, f0[0], acc[0]);   acc[1] = fmaf(w, f0[1], acc[1]);
      acc[2] = fmaf(w, f1[0], acc[2]);   acc[3] = fmaf(w, f1[1], acc[3]);
      acc[4] = fmaf(w, f2[0], acc[4]);   acc[5] = fmaf(w, f2[1], acc[5]);
      acc[6] = fmaf(w, f3[0], acc[6]);   acc[7] = fmaf(w, f3[1], acc[7]);
      acc[8] = fmaf(w, f4[0], acc[8]);   acc[9] = fmaf(w, f4[1], acc[9]);
      acc[10] = fmaf(w, f5[0], acc[10]); acc[11] = fmaf(w, f5[1], acc[11]);
      acc[12] = fmaf(w, f6[0], acc[12]); acc[13] = fmaf(w, f6[1], acc[13]);
      acc[14] = fmaf(w, f7[0], acc[14]); acc[15] = fmaf(w, f7[1], acc[15]);
    }
  }

  const unsigned dg = end - beg;
  const float inv = dg ? 1.f / (float)dg : 0.f;
  uint4 pk0, pk1;
  pk0.x = pack2bf(acc[0] * inv, acc[1] * inv);
  pk0.y = pack2bf(acc[2] * inv, acc[3] * inv);
  pk0.z = pack2bf(acc[4] * inv, acc[5] * inv);
  pk0.w = pack2bf(acc[6] * inv, acc[7] * inv);
  pk1.x = pack2bf(acc[8] * inv, acc[9] * inv);
  pk1.y = pack2bf(acc[10] * inv, acc[11] * inv);
  pk1.z = pack2bf(acc[12] * inv, acc[13] * inv);
  pk1.w = pack2bf(acc[14] * inv, acc[15] * inv);
  *(uint4*)&mlds[lrow * MSTRIDE + p * 8] = pk0;
  *(uint4*)&mlds[lrow * MSTRIDE + p * 8 + 4] = pk1;
  __syncthreads();

  // ---- GEMM phase: 64 rows x dual 32 cols ----
  const int tx = tid & 7;
  const int ty = tid >> 3;  // 0..31
  const int arow = ty * 2;

  const uint2* mp[2];
  const uint2* sp[2];
#pragma unroll
  for (int r = 0; r < 2; ++r) {
    long long gr = node0 + arow + r;
    if (gr >= M) gr = M - 1;
    mp[r] = (const uint2*)&mlds[(arow + r) * MSTRIDE];
    sp[r] = (const uint2*)(xsb + gr * 64);
  }

  float4 an[2], as[2];
#pragma unroll
  for (int r = 0; r < 2; ++r) {
    an[r] = make_float4(0.f, 0.f, 0.f, 0.f);
    as[r] = make_float4(0.f, 0.f, 0.f, 0.f);
  }

#pragma unroll 2
  for (int k4 = 0; k4 < 16; ++k4) {
    float4 a[2];
#pragma unroll
    for (int r = 0; r < 2; ++r) a[r] = relu_mix(mp[r][k4], sp[r][k4]);
    float4 wn0 = *(const float4*)&Wn[(4 * k4 + 0) * 32 + 4 * tx];
    float4 wn1 = *(const float4*)&Wn[(4 * k4 + 1) * 32 + 4 * tx];
    float4 wn2 = *(const float4*)&Wn[(4 * k4 + 2) * 32 + 4 * tx];
    float4 wn3 = *(const float4*)&Wn[(4 * k4 + 3) * 32 + 4 * tx];
    float4 ws0 = *(const float4*)&Ws[(4 * k4 + 0) * 32 + 4 * tx];
    float4 ws1 = *(const float4*)&Ws[(4 * k4 + 1) * 32 + 4 * tx];
    float4 ws2 = *(const float4*)&Ws[(4 * k4 + 2) * 32 + 4 * tx];
    float4 ws3 = *(const float4*)&Ws[(4 * k4 + 3) * 32 + 4 * tx];
#pragma unroll
    for (int r = 0; r < 2; ++r) {
      fma4(a[r].x, wn0, an[r]);
      fma4(a[r].y, wn1, an[r]);
      fma4(a[r].z, wn2, an[r]);
      fma4(a[r].w, wn3, an[r]);
      fma4(a[r].x, ws0, as[r]);
      fma4(a[r].y, ws1, as[r]);
      fma4(a[r].z, ws2, as[r]);
      fma4(a[r].w, ws3, as[r]);
    }
  }

  const float4 bv = *(const float4*)&b2[4 * tx];
#pragma unroll
  for (int r = 0; r < 2; ++r) {
    int row = node0 + arow + r;
    if (row < M) {
      float4 o;
      o.x = as[r].x + bv.x;
      o.y = as[r].y + bv.y;
      o.z = as[r].z + bv.z;
      o.w = as[r].w + bv.w;
      *(float4*)&hs[(long long)row * 32 + 4 * tx] = o;
      hnb8[(size_t)row * 8 + tx] =
          packfp8x4(an[r].x, an[r].y, an[r].z, an[r].w);
    }
  }
}

// ---------------------------------------------------------------------------
// gather2: out[node][:] = mean_j fp8decode(hnb8[ssrc[j]][:]) + hs[node][:]
// Row = 32 fp8 = 32 B; table 3.2 MB -> L2-resident. P=2 lanes/node.
// ---------------------------------------------------------------------------
__global__ __launch_bounds__(256) void gather2_k(
    const uint4* __restrict__ valb4, const int* __restrict__ ssrc,
    const uint2* __restrict__ rows2, const float* __restrict__ base,
    float* __restrict__ out, int N) {
  constexpr int P = 2;
  const int node = blockIdx.x * 128 + threadIdx.x / P;
  const int p = threadIdx.x & 1;
  if (node >= N) return;
  const uint2 be = rows2[node];
  const unsigned beg = be.x, end = be.y;

  float acc[16];
#pragma unroll
  for (int q = 0; q < 16; ++q) acc[q] = 0.f;

  unsigned j = beg;
  for (; j + 8 <= end; j += 8) {
    int sn[8];
#pragma unroll
    for (int i = 0; i < 8; ++i) sn[i] = ssrc[j + i];
    uint4 u[8];
#pragma unroll
    for (int i = 0; i < 8; ++i) u[i] = valb4[(size_t)sn[i] * P + p];
#pragma unroll
    for (int i = 0; i < 8; ++i) {
      v2f f0 = __builtin_amdgcn_cvt_pk_f32_fp8((int)u[i].x, false);
      v2f f1 = __builtin_amdgcn_cvt_pk_f32_fp8((int)u[i].x, true);
      v2f f2 = __builtin_amdgcn_cvt_pk_f32_fp8((int)u[i].y, false);
      v2f f3 = __builtin_amdgcn_cvt_pk_f32_fp8((int)u[i].y, true);
      v2f f4 = __builtin_amdgcn_cvt_pk_f32_fp8((int)u[i].z, false);
      v2f f5 = __builtin_amdgcn_cvt_pk_f32_fp8((int)u[i].z, true);
      v2f f6 = __builtin_amdgcn_cvt_pk_f32_fp8((int)u[i].w, false);
      v2f f7 = __builtin_amdgcn_cvt_pk_f32_fp8((int)u[i].w, true);
      acc[0] += f0[0];  acc[1] += f0[1];
      acc[2] += f1[0];  acc[3] += f1[1];
      acc[4] += f2[0];  acc[5] += f2[1];
      acc[6] += f3[0];  acc[7] += f3[1];
      acc[8] += f4[0];  acc[9] += f4[1];
      acc[10] += f5[0]; acc[11] += f5[1];
      acc[12] += f6[0]; acc[13] += f6[1];
      acc[14] += f7[0]; acc[15] += f7[1];
    }
  }
  if (j < end) {
    const unsigned last = end - 1;
    int sn[8];
#pragma unroll
    for (int i = 0; i < 8; ++i) {
      unsigned jj = j + i;
      sn[i] = ssrc[jj < last ? jj : last];
    }
    uint4 u[8];
#pragma unroll
    for (int i = 0; i < 8; ++i) u[i] = valb4[(size_t)sn[i] * P + p];
#pragma unroll
    for (int i = 0; i < 8; ++i) {
      float w = ((j + i) < end) ? 1.f : 0.f;
      v2f f0 = __builtin_amdgcn_cvt_pk_f32_fp8((int)u[i].x, false);
      v2f f1 = __builtin_amdgcn_cvt_pk_f32_fp8((int)u[i].x, true);
      v2f f2 = __builtin_amdgcn_cvt_pk_f32_fp8((int)u[i].y, false);
      v2f f3 = __builtin_amdgcn_cvt_pk_f32_fp8((int)u[i].y, true);
      v2f f4 = __builtin_amdgcn_cvt_pk_f32_fp8((int)u[i].z, false);
      v2f f5 = __builtin_amdgcn_cvt_pk_f32_fp8((int)u[i].z, true);
      v2f f6 = __builtin_amdgcn_cvt_pk_f32_fp8((int)u[i].w, false);
      v2f f7 = __builtin_amdgcn_cvt_pk_f32_fp8((int)u[i].w, true);
      acc[0] = fmaf(w, f0[0], acc[0]);   acc[1] = fmaf(w, f0[1], acc[1]);
      acc[2] = fmaf(w, f1[0], acc[2]);   acc[3] = fmaf(w, f1[1], acc[3]);
      acc[4] = fmaf(w, f2[0], acc[4]);   acc[5] = fmaf(w, f2[1], acc[5]);
      acc[6] = fmaf(w, f3[0], acc[6]);   acc[7] = fmaf(w, f3[1], acc[7]);
      acc[8] = fmaf(w, f4[0], acc[8]);   acc[9] = fmaf(w, f4[1], acc[9]);
      acc[10] = fmaf(w, f5[0], acc[10]); acc[11] = fmaf(w, f5[1], acc[11]);
      acc[12] = fmaf(w, f6[0], acc[12]); acc[13] = fmaf(w, f6[1], acc[13]);
      acc[14] = fmaf(w, f7[0], acc[14]); acc[15] = fmaf(w, f7[1], acc[15]);
    }
  }

  const unsigned dg = end - beg;
  const float inv = dg ? 1.f / (float)dg : 0.f;
  const size_t o = (size_t)node * 32 + 16 * p;
#pragma unroll
  for (int q4 = 0; q4 < 4; ++q4) {
    float4 bv = *(const float4*)&base[o + 4 * q4];
    float4 ov;
    ov.x = acc[4 * q4 + 0] * inv + bv.x;
    ov.y = acc[4 * q4 + 1] * inv + bv.y;
    ov.z = acc[4 * q4 + 2] * inv + bv.z;
    ov.w = acc[4 * q4 + 3] * inv + bv.w;
    *(float4*)&out[o + 4 * q4] = ov;
  }
}

extern "C" void kernel_launch(void* const* d_in, const int* in_sizes, int n_in,
                              void* d_out, int out_size, void* d_ws,
                              size_t ws_size, hipStream_t stream) {
  const float* x   = (const float*)d_in[0];
  const int*   ei  = (const int*)d_in[1];  // [2, E]: row0 = src, row1 = dst
  const float* W1n = (const float*)d_in[2];
  const float* W1s = (const float*)d_in[3];
  const float* b1  = (const float*)d_in[4];
  const float* W2n = (const float*)d_in[5];
  const float* W2s = (const float*)d_in[6];
  const float* b2  = (const float*)d_in[7];
  float* out = (float*)d_out;

  const int E = in_sizes[1] / 2;  // 1,600,000
  const int M = N_NODES;
  const int* src = ei;
  const int* dst = ei + E;

  // Workspace layout (bytes):
  //   ep    @ 0           12,845,056  (NB*CAP u32; layer2: hnb8 aliases, dead
  //                                    after bsort)
  //   ssrc  @ 12,845,056  12,845,056
  //   rows2 @ 25,690,112     802,816
  //   bcur  @ 26,492,928       3,136
  //   xnb8  @ 26,496,064   6,400,000  (fp8 M x 64)
  //   xsb   @ 32,896,064  12,800,000  (bf16 M x 64)
  //   hs    @ 45,696,064  12,800,000  (f32 M x 32)
  char* wsb = (char*)d_ws;
  unsigned*       ep    = (unsigned*)(wsb);
  int*            ssrc  = (int*)(wsb + 12845056);
  uint2*          rows2 = (uint2*)(wsb + 25690112);
  unsigned*       bcur  = (unsigned*)(wsb + 26492928);
  unsigned*       xnb8  = (unsigned*)(wsb + 26496064);
  unsigned short* xsb   = (unsigned short*)(wsb + 32896064);
  float*          hs    = (float*)(wsb + 45696064);
  unsigned*       hnb8  = (unsigned*)(wsb);  // aliases ep (dead after bsort)

  // 1) zero bucket cursors (3 KB)
  hipMemsetAsync(bcur, 0, NB * 4, stream);
  // 2) fusedB: homogeneous blocks; per-edge atomic scatter + layer-1 dual-GEMM
  fusedB_k<<<GB1, 256, 0, stream>>>(src, dst, bcur, ep, x, W1n, W1s, b1,
                                    xnb8, xsb, E, M);
  // 3) per-bucket counting sort -> ssrc runs + rows2
  bsort_k<<<NB, 256, 0, stream>>>(ep, bcur, ssrc, rows2);
  // 4) fused gather1 + gemm2: mean1 lives in LDS only
  fgg_k<<<GB1, 256, 0, stream>>>((const uint4*)xnb8, ssrc, rows2, xsb, W2n,
                                 W2s, b2, hnb8, hs, M);
  // 5) out = mean(fp8(hn)[src]) + hs
  gather2_k<<<(M + 127) / 128, 256, 0, stream>>>((const uint4*)hnb8, ssrc,
                                                 rows2, hs, out, M);
}

// Round 6
// 270.059 us; speedup vs baseline: 2.0120x; 2.0120x over previous
//
#include <hip/hip_runtime.h>
#include <hip/hip_bf16.h>

#define N_NODES 100000
#define NPAD 100352    // 1563*64 = 100032 rounded up to 64; dcnt/ssrc sized NPAD
#define DCAP 64        // static per-node capacity (mean deg 16, P(>64) ~ 1e-22)
#define MSTRIDE 36     // u32 stride of an LDS mean row (32 payload + 4 pad)

typedef float v2f __attribute__((ext_vector_type(2)));

__device__ inline void fma4(float a, const float4& w, float4& c) {
  c.x = fmaf(a, w.x, c.x);
  c.y = fmaf(a, w.y, c.y);
  c.z = fmaf(a, w.z, c.z);
  c.w = fmaf(a, w.w, c.w);
}
__device__ inline unsigned short f2bf(float f) {  // RNE f32->bf16
  unsigned u = __float_as_uint(f);
  u += 0x7fffu + ((u >> 16) & 1u);
  return (unsigned short)(u >> 16);
}
__device__ inline unsigned pack2bf(float a, float b) {
  return (unsigned)f2bf(a) | ((unsigned)f2bf(b) << 16);
}
__device__ inline unsigned packfp8x4(float a, float b, float c, float d) {
  int pk = __builtin_amdgcn_cvt_pk_fp8_f32(a, b, 0, false);
  pk = __builtin_amdgcn_cvt_pk_fp8_f32(c, d, pk, true);
  return (unsigned)pk;
}
// relu(bf16(m) + bf16(s)) for 4 packed bf16 elements (bit-identical f32 math)
__device__ inline float4 relu_mix(uint2 m, uint2 s) {
  float4 v;
  v.x = fmaxf(__uint_as_float(m.x << 16) + __uint_as_float(s.x << 16), 0.f);
  v.y = fmaxf(__uint_as_float(m.x & 0xffff0000u) +
                  __uint_as_float(s.x & 0xffff0000u), 0.f);
  v.z = fmaxf(__uint_as_float(m.y << 16) + __uint_as_float(s.y << 16), 0.f);
  v.w = fmaxf(__uint_as_float(m.y & 0xffff0000u) +
                  __uint_as_float(s.y & 0xffff0000u), 0.f);
  return v;
}

#define GB1 1563   // ceil(100000/64); 1563*1024 = 1,600,512 >= E
#define SEPB 1024  // edges scattered per block (4/thread)

// ---------------------------------------------------------------------------
// R19 fusedC: homogeneous blocks; per-edge scatter DIRECTLY into the final
// node-sorted ssrc layout (r = atomicAdd(&dcnt[dst],1); ssrc[dst*64+r]=src),
// then the 64-row layer-1 dual-GEMM tile. R5 failed on 2040 same-address
// atomics/counter (784 buckets); node-level = 16/counter -> no serialization.
// Deletes ep, bsort_k and rows2 entirely; a node's run fills its cache line
// contiguously (LLC write-combining).
// ---------------------------------------------------------------------------
__global__ __launch_bounds__(256) void fusedC_k(
    const int* __restrict__ src, const int* __restrict__ dst,
    unsigned* __restrict__ dcnt, int* __restrict__ ssrc,
    const float* __restrict__ x, const float* __restrict__ W1n,
    const float* __restrict__ W1s, const float* __restrict__ b1,
    unsigned* __restrict__ xnb8, unsigned short* __restrict__ xsb,
    int E, int M) {
  __shared__ __align__(16) float smem[8192];  // 32768 B
  float* Wn = smem;
  float* Ws = smem + 4096;
  const int tid = threadIdx.x;
  const int bid = blockIdx.x;

  // ---- scatter prologue: 4 edges/thread, fully independent chains ----
  const int ebase = bid * SEPB;
  int es[4], ed[4];
  bool ev[4];
#pragma unroll
  for (int it = 0; it < 4; ++it) {
    int e = ebase + it * 256 + tid;
    ev[it] = (e < E);
    if (ev[it]) {
      es[it] = src[e];
      ed[it] = dst[e];
    }
  }

  // weight staging issues while edge loads are in flight
  for (int i = tid; i < 1024; i += 256) {
    ((float4*)Wn)[i] = ((const float4*)W1n)[i];
    ((float4*)Ws)[i] = ((const float4*)W1s)[i];
  }

#pragma unroll
  for (int it = 0; it < 4; ++it) {
    if (ev[it]) {
      unsigned r = atomicAdd(&dcnt[ed[it]], 1u);
      if (r < DCAP) ssrc[((size_t)ed[it] << 6) + r] = es[it];
    }
  }

  // ---- gemm1 body ----
  const int row0 = bid * 64;
  const int tx = tid & 15;
  const int ty = tid >> 4;
  const int arow = ty * 4;

  // clamped per-row global pointers (A reads are 16-lane broadcasts via L1)
  const float* xr[4];
#pragma unroll
  for (int r = 0; r < 4; ++r) {
    long long gr = row0 + arow + r;
    if (gr >= M) gr = M - 1;
    xr[r] = x + gr * 64;
  }

  float4 an[4], as[4];
#pragma unroll
  for (int r = 0; r < 4; ++r) {
    an[r] = make_float4(0.f, 0.f, 0.f, 0.f);
    as[r] = make_float4(0.f, 0.f, 0.f, 0.f);
  }
  __syncthreads();

#pragma unroll 2
  for (int k4 = 0; k4 < 16; ++k4) {
    float4 a[4];
#pragma unroll
    for (int r = 0; r < 4; ++r) a[r] = *(const float4*)(xr[r] + 4 * k4);
    float4 wn0 = *(const float4*)&Wn[(4 * k4 + 0) * 64 + 4 * tx];
    float4 wn1 = *(const float4*)&Wn[(4 * k4 + 1) * 64 + 4 * tx];
    float4 wn2 = *(const float4*)&Wn[(4 * k4 + 2) * 64 + 4 * tx];
    float4 wn3 = *(const float4*)&Wn[(4 * k4 + 3) * 64 + 4 * tx];
    float4 ws0 = *(const float4*)&Ws[(4 * k4 + 0) * 64 + 4 * tx];
    float4 ws1 = *(const float4*)&Ws[(4 * k4 + 1) * 64 + 4 * tx];
    float4 ws2 = *(const float4*)&Ws[(4 * k4 + 2) * 64 + 4 * tx];
    float4 ws3 = *(const float4*)&Ws[(4 * k4 + 3) * 64 + 4 * tx];
#pragma unroll
    for (int r = 0; r < 4; ++r) {
      fma4(a[r].x, wn0, an[r]);
      fma4(a[r].y, wn1, an[r]);
      fma4(a[r].z, wn2, an[r]);
      fma4(a[r].w, wn3, an[r]);
      fma4(a[r].x, ws0, as[r]);
      fma4(a[r].y, ws1, as[r]);
      fma4(a[r].z, ws2, as[r]);
      fma4(a[r].w, ws3, as[r]);
    }
  }

  const float4 bv = *(const float4*)&b1[4 * tx];
#pragma unroll
  for (int r = 0; r < 4; ++r) {
    int row = row0 + arow + r;
    if (row < M) {
      ushort4 ps;
      ps.x = f2bf(as[r].x + bv.x);
      ps.y = f2bf(as[r].y + bv.y);
      ps.z = f2bf(as[r].z + bv.z);
      ps.w = f2bf(as[r].w + bv.w);
      *(ushort4*)&xsb[(long long)row * 64 + 4 * tx] = ps;
      xnb8[(size_t)row * 16 + tx] =
          packfp8x4(an[r].x, an[r].y, an[r].z, an[r].w);
    }
  }
}

// ---------------------------------------------------------------------------
// fgg: fused gather1 + gemm2 per 64 nodes. Gather phase computes
// mean_j fp8decode(xnb8[ssrc[node*64 + j]]) -> bf16-packed rows in LDS;
// GEMM phase does hn(fp8)/hs = relu(mean+xs)@{W2n,W2s}+b2.
// Run bounds now come from dcnt (beg = node<<6, end = beg + dcnt[node]).
// ---------------------------------------------------------------------------
__global__ __launch_bounds__(256) void fgg_k(
    const uint4* __restrict__ valb4, const int* __restrict__ ssrc,
    const unsigned* __restrict__ dcnt, const unsigned short* __restrict__ xsb,
    const float* __restrict__ W2n, const float* __restrict__ W2s,
    const float* __restrict__ b2, unsigned* __restrict__ hnb8,
    float* __restrict__ hs, int M) {
  __shared__ float Wn[64 * 32];
  __shared__ float Ws[64 * 32];
  __shared__ unsigned mlds[64 * MSTRIDE];  // 9216 B
  const int tid = threadIdx.x;
  const int node0 = blockIdx.x * 64;

  for (int i = tid; i < 512; i += 256) {
    ((float4*)Wn)[i] = ((const float4*)W2n)[i];
    ((float4*)Ws)[i] = ((const float4*)W2s)[i];
  }

  // ---- gather phase: P=4 lanes per node, 16 cols each ----
  constexpr int P = 4;
  const int lrow = tid / P;            // 0..63
  const int node = node0 + lrow;       // < 100032 <= NPAD (dcnt=0 beyond M)
  const int p = tid & 3;
  const unsigned dg = dcnt[node];
  const unsigned beg = ((unsigned)node) << 6;
  const unsigned end = beg + dg;

  float acc[16];
#pragma unroll
  for (int q = 0; q < 16; ++q) acc[q] = 0.f;

  unsigned j = beg;
  for (; j + 8 <= end; j += 8) {
    int sn[8];
#pragma unroll
    for (int i = 0; i < 8; ++i) sn[i] = ssrc[j + i];
    uint4 u[8];
#pragma unroll
    for (int i = 0; i < 8; ++i) u[i] = valb4[(size_t)sn[i] * P + p];
#pragma unroll
    for (int i = 0; i < 8; ++i) {
      v2f f0 = __builtin_amdgcn_cvt_pk_f32_fp8((int)u[i].x, false);
      v2f f1 = __builtin_amdgcn_cvt_pk_f32_fp8((int)u[i].x, true);
      v2f f2 = __builtin_amdgcn_cvt_pk_f32_fp8((int)u[i].y, false);
      v2f f3 = __builtin_amdgcn_cvt_pk_f32_fp8((int)u[i].y, true);
      v2f f4 = __builtin_amdgcn_cvt_pk_f32_fp8((int)u[i].z, false);
      v2f f5 = __builtin_amdgcn_cvt_pk_f32_fp8((int)u[i].z, true);
      v2f f6 = __builtin_amdgcn_cvt_pk_f32_fp8((int)u[i].w, false);
      v2f f7 = __builtin_amdgcn_cvt_pk_f32_fp8((int)u[i].w, true);
      acc[0] += f0[0];  acc[1] += f0[1];
      acc[2] += f1[0];  acc[3] += f1[1];
      acc[4] += f2[0];  acc[5] += f2[1];
      acc[6] += f3[0];  acc[7] += f3[1];
      acc[8] += f4[0];  acc[9] += f4[1];
      acc[10] += f5[0]; acc[11] += f5[1];
      acc[12] += f6[0]; acc[13] += f6[1];
      acc[14] += f7[0]; acc[15] += f7[1];
    }
  }
  if (j < end) {
    const unsigned last = end - 1;
    int sn[8];
#pragma unroll
    for (int i = 0; i < 8; ++i) {
      unsigned jj = j + i;
      sn[i] = ssrc[jj < last ? jj : last];
    }
    uint4 u[8];
#pragma unroll
    for (int i = 0; i < 8; ++i) u[i] = valb4[(size_t)sn[i] * P + p];
#pragma unroll
    for (int i = 0; i < 8; ++i) {
      float w = ((j + i) < end) ? 1.f : 0.f;
      v2f f0 = __builtin_amdgcn_cvt_pk_f32_fp8((int)u[i].x, false);
      v2f f1 = __builtin_amdgcn_cvt_pk_f32_fp8((int)u[i].x, true);
      v2f f2 = __builtin_amdgcn_cvt_pk_f32_fp8((int)u[i].y, false);
      v2f f3 = __builtin_amdgcn_cvt_pk_f32_fp8((int)u[i].y, true);
      v2f f4 = __builtin_amdgcn_cvt_pk_f32_fp8((int)u[i].z, false);
      v2f f5 = __builtin_amdgcn_cvt_pk_f32_fp8((int)u[i].z, true);
      v2f f6 = __builtin_amdgcn_cvt_pk_f32_fp8((int)u[i].w, false);
      v2f f7 = __builtin_amdgcn_cvt_pk_f32_fp8((int)u[i].w, true);
      acc[0] = fmaf(w, f0[0], acc[0]);   acc[1] = fmaf(w, f0[1], acc[1]);
      acc[2] = fmaf(w, f1[0], acc[2]);   acc[3] = fmaf(w, f1[1], acc[3]);
      acc[4] = fmaf(w, f2[0], acc[4]);   acc[5] = fmaf(w, f2[1], acc[5]);
      acc[6] = fmaf(w, f3[0], acc[6]);   acc[7] = fmaf(w, f3[1], acc[7]);
      acc[8] = fmaf(w, f4[0], acc[8]);   acc[9] = fmaf(w, f4[1], acc[9]);
      acc[10] = fmaf(w, f5[0], acc[10]); acc[11] = fmaf(w, f5[1], acc[11]);
      acc[12] = fmaf(w, f6[0], acc[12]); acc[13] = fmaf(w, f6[1], acc[13]);
      acc[14] = fmaf(w, f7[0], acc[14]); acc[15] = fmaf(w, f7[1], acc[15]);
    }
  }

  const float inv = dg ? 1.f / (float)dg : 0.f;
  uint4 pk0, pk1;
  pk0.x = pack2bf(acc[0] * inv, acc[1] * inv);
  pk0.y = pack2bf(acc[2] * inv, acc[3] * inv);
  pk0.z = pack2bf(acc[4] * inv, acc[5] * inv);
  pk0.w = pack2bf(acc[6] * inv, acc[7] * inv);
  pk1.x = pack2bf(acc[8] * inv, acc[9] * inv);
  pk1.y = pack2bf(acc[10] * inv, acc[11] * inv);
  pk1.z = pack2bf(acc[12] * inv, acc[13] * inv);
  pk1.w = pack2bf(acc[14] * inv, acc[15] * inv);
  *(uint4*)&mlds[lrow * MSTRIDE + p * 8] = pk0;
  *(uint4*)&mlds[lrow * MSTRIDE + p * 8 + 4] = pk1;
  __syncthreads();

  // ---- GEMM phase: 64 rows x dual 32 cols ----
  const int tx = tid & 7;
  const int ty = tid >> 3;  // 0..31
  const int arow = ty * 2;

  const uint2* mp[2];
  const uint2* sp[2];
#pragma unroll
  for (int r = 0; r < 2; ++r) {
    long long gr = node0 + arow + r;
    if (gr >= M) gr = M - 1;
    mp[r] = (const uint2*)&mlds[(arow + r) * MSTRIDE];
    sp[r] = (const uint2*)(xsb + gr * 64);
  }

  float4 an[2], as[2];
#pragma unroll
  for (int r = 0; r < 2; ++r) {
    an[r] = make_float4(0.f, 0.f, 0.f, 0.f);
    as[r] = make_float4(0.f, 0.f, 0.f, 0.f);
  }

#pragma unroll 2
  for (int k4 = 0; k4 < 16; ++k4) {
    float4 a[2];
#pragma unroll
    for (int r = 0; r < 2; ++r) a[r] = relu_mix(mp[r][k4], sp[r][k4]);
    float4 wn0 = *(const float4*)&Wn[(4 * k4 + 0) * 32 + 4 * tx];
    float4 wn1 = *(const float4*)&Wn[(4 * k4 + 1) * 32 + 4 * tx];
    float4 wn2 = *(const float4*)&Wn[(4 * k4 + 2) * 32 + 4 * tx];
    float4 wn3 = *(const float4*)&Wn[(4 * k4 + 3) * 32 + 4 * tx];
    float4 ws0 = *(const float4*)&Ws[(4 * k4 + 0) * 32 + 4 * tx];
    float4 ws1 = *(const float4*)&Ws[(4 * k4 + 1) * 32 + 4 * tx];
    float4 ws2 = *(const float4*)&Ws[(4 * k4 + 2) * 32 + 4 * tx];
    float4 ws3 = *(const float4*)&Ws[(4 * k4 + 3) * 32 + 4 * tx];
#pragma unroll
    for (int r = 0; r < 2; ++r) {
      fma4(a[r].x, wn0, an[r]);
      fma4(a[r].y, wn1, an[r]);
      fma4(a[r].z, wn2, an[r]);
      fma4(a[r].w, wn3, an[r]);
      fma4(a[r].x, ws0, as[r]);
      fma4(a[r].y, ws1, as[r]);
      fma4(a[r].z, ws2, as[r]);
      fma4(a[r].w, ws3, as[r]);
    }
  }

  const float4 bv = *(const float4*)&b2[4 * tx];
#pragma unroll
  for (int r = 0; r < 2; ++r) {
    int row = node0 + arow + r;
    if (row < M) {
      float4 o;
      o.x = as[r].x + bv.x;
      o.y = as[r].y + bv.y;
      o.z = as[r].z + bv.z;
      o.w = as[r].w + bv.w;
      *(float4*)&hs[(long long)row * 32 + 4 * tx] = o;
      hnb8[(size_t)row * 8 + tx] =
          packfp8x4(an[r].x, an[r].y, an[r].z, an[r].w);
    }
  }
}

// ---------------------------------------------------------------------------
// gather2: out[node][:] = mean_j fp8decode(hnb8[ssrc[node*64+j]][:]) +
// hs[node][:]. Row = 32 fp8 = 32 B; table 3.2 MB -> L2-resident. P=2.
// ---------------------------------------------------------------------------
__global__ __launch_bounds__(256) void gather2_k(
    const uint4* __restrict__ valb4, const int* __restrict__ ssrc,
    const unsigned* __restrict__ dcnt, const float* __restrict__ base,
    float* __restrict__ out, int N) {
  constexpr int P = 2;
  const int node = blockIdx.x * 128 + threadIdx.x / P;
  const int p = threadIdx.x & 1;
  if (node >= N) return;
  const unsigned dg = dcnt[node];
  const unsigned beg = ((unsigned)node) << 6;
  const unsigned end = beg + dg;

  float acc[16];
#pragma unroll
  for (int q = 0; q < 16; ++q) acc[q] = 0.f;

  unsigned j = beg;
  for (; j + 8 <= end; j += 8) {
    int sn[8];
#pragma unroll
    for (int i = 0; i < 8; ++i) sn[i] = ssrc[j + i];
    uint4 u[8];
#pragma unroll
    for (int i = 0; i < 8; ++i) u[i] = valb4[(size_t)sn[i] * P + p];
#pragma unroll
    for (int i = 0; i < 8; ++i) {
      v2f f0 = __builtin_amdgcn_cvt_pk_f32_fp8((int)u[i].x, false);
      v2f f1 = __builtin_amdgcn_cvt_pk_f32_fp8((int)u[i].x, true);
      v2f f2 = __builtin_amdgcn_cvt_pk_f32_fp8((int)u[i].y, false);
      v2f f3 = __builtin_amdgcn_cvt_pk_f32_fp8((int)u[i].y, true);
      v2f f4 = __builtin_amdgcn_cvt_pk_f32_fp8((int)u[i].z, false);
      v2f f5 = __builtin_amdgcn_cvt_pk_f32_fp8((int)u[i].z, true);
      v2f f6 = __builtin_amdgcn_cvt_pk_f32_fp8((int)u[i].w, false);
      v2f f7 = __builtin_amdgcn_cvt_pk_f32_fp8((int)u[i].w, true);
      acc[0] += f0[0];  acc[1] += f0[1];
      acc[2] += f1[0];  acc[3] += f1[1];
      acc[4] += f2[0];  acc[5] += f2[1];
      acc[6] += f3[0];  acc[7] += f3[1];
      acc[8] += f4[0];  acc[9] += f4[1];
      acc[10] += f5[0]; acc[11] += f5[1];
      acc[12] += f6[0]; acc[13] += f6[1];
      acc[14] += f7[0]; acc[15] += f7[1];
    }
  }
  if (j < end) {
    const unsigned last = end - 1;
    int sn[8];
#pragma unroll
    for (int i = 0; i < 8; ++i) {
      unsigned jj = j + i;
      sn[i] = ssrc[jj < last ? jj : last];
    }
    uint4 u[8];
#pragma unroll
    for (int i = 0; i < 8; ++i) u[i] = valb4[(size_t)sn[i] * P + p];
#pragma unroll
    for (int i = 0; i < 8; ++i) {
      float w = ((j + i) < end) ? 1.f : 0.f;
      v2f f0 = __builtin_amdgcn_cvt_pk_f32_fp8((int)u[i].x, false);
      v2f f1 = __builtin_amdgcn_cvt_pk_f32_fp8((int)u[i].x, true);
      v2f f2 = __builtin_amdgcn_cvt_pk_f32_fp8((int)u[i].y, false);
      v2f f3 = __builtin_amdgcn_cvt_pk_f32_fp8((int)u[i].y, true);
      v2f f4 = __builtin_amdgcn_cvt_pk_f32_fp8((int)u[i].z, false);
      v2f f5 = __builtin_amdgcn_cvt_pk_f32_fp8((int)u[i].z, true);
      v2f f6 = __builtin_amdgcn_cvt_pk_f32_fp8((int)u[i].w, false);
      v2f f7 = __builtin_amdgcn_cvt_pk_f32_fp8((int)u[i].w, true);
      acc[0] = fmaf(w, f0[0], acc[0]);   acc[1] = fmaf(w, f0[1], acc[1]);
      acc[2] = fmaf(w, f1[0], acc[2]);   acc[3] = fmaf(w, f1[1], acc[3]);
      acc[4] = fmaf(w, f2[0], acc[4]);   acc[5] = fmaf(w, f2[1], acc[5]);
      acc[6] = fmaf(w, f3[0], acc[6]);   acc[7] = fmaf(w, f3[1], acc[7]);
      acc[8] = fmaf(w, f4[0], acc[8]);   acc[9] = fmaf(w, f4[1], acc[9]);
      acc[10] = fmaf(w, f5[0], acc[10]); acc[11] = fmaf(w, f5[1], acc[11]);
      acc[12] = fmaf(w, f6[0], acc[12]); acc[13] = fmaf(w, f6[1], acc[13]);
      acc[14] = fmaf(w, f7[0], acc[14]); acc[15] = fmaf(w, f7[1], acc[15]);
    }
  }

  const float inv = dg ? 1.f / (float)dg : 0.f;
  const size_t o = (size_t)node * 32 + 16 * p;
#pragma unroll
  for (int q4 = 0; q4 < 4; ++q4) {
    float4 bv = *(const float4*)&base[o + 4 * q4];
    float4 ov;
    ov.x = acc[4 * q4 + 0] * inv + bv.x;
    ov.y = acc[4 * q4 + 1] * inv + bv.y;
    ov.z = acc[4 * q4 + 2] * inv + bv.z;
    ov.w = acc[4 * q4 + 3] * inv + bv.w;
    *(float4*)&out[o + 4 * q4] = ov;
  }
}

extern "C" void kernel_launch(void* const* d_in, const int* in_sizes, int n_in,
                              void* d_out, int out_size, void* d_ws,
                              size_t ws_size, hipStream_t stream) {
  const float* x   = (const float*)d_in[0];
  const int*   ei  = (const int*)d_in[1];  // [2, E]: row0 = src, row1 = dst
  const float* W1n = (const float*)d_in[2];
  const float* W1s = (const float*)d_in[3];
  const float* b1  = (const float*)d_in[4];
  const float* W2n = (const float*)d_in[5];
  const float* W2s = (const float*)d_in[6];
  const float* b2  = (const float*)d_in[7];
  float* out = (float*)d_out;

  const int E = in_sizes[1] / 2;  // 1,600,000
  const int M = N_NODES;
  const int* src = ei;
  const int* dst = ei + E;

  // Workspace layout (bytes):
  //   ssrc  @ 0           25,690,112  (NPAD * 64 * 4: node-sorted src lists)
  //   dcnt  @ 25,690,112     401,408  (NPAD u32 degree counters)
  //   xnb8  @ 26,091,520   6,400,000  (fp8 M x 64)
  //   xsb   @ 32,491,520  12,800,000  (bf16 M x 64)
  //   hnb8  @ 45,291,520   3,211,264  (fp8 M x 32)
  //   hs    @ 48,502,784  12,800,000  (f32 M x 32)
  char* wsb = (char*)d_ws;
  int*            ssrc  = (int*)(wsb);
  unsigned*       dcnt  = (unsigned*)(wsb + 25690112);
  unsigned*       xnb8  = (unsigned*)(wsb + 26091520);
  unsigned short* xsb   = (unsigned short*)(wsb + 32491520);
  unsigned*       hnb8  = (unsigned*)(wsb + 45291520);
  float*          hs    = (float*)(wsb + 48502784);

  // 1) zero node degree counters (400 KB)
  hipMemsetAsync(dcnt, 0, NPAD * 4, stream);
  // 2) fusedC: per-edge node-level scatter (final layout) + layer-1 dual-GEMM
  fusedC_k<<<GB1, 256, 0, stream>>>(src, dst, dcnt, ssrc, x, W1n, W1s, b1,
                                    xnb8, xsb, E, M);
  // 3) fused gather1 + gemm2: mean1 lives in LDS only
  fgg_k<<<GB1, 256, 0, stream>>>((const uint4*)xnb8, ssrc, dcnt, xsb, W2n,
                                 W2s, b2, hnb8, hs, M);
  // 4) out = mean(fp8(hn)[src]) + hs
  gather2_k<<<(M + 127) / 128, 256, 0, stream>>>((const uint4*)hnb8, ssrc,
                                                 dcnt, hs, out, M);
}

// Round 7
// 216.147 us; speedup vs baseline: 2.5138x; 1.2494x over previous
//
#include <hip/hip_runtime.h>
#include <hip/hip_bf16.h>

#define N_NODES 100000
#define NB 784   // buckets of 128 nodes: 784*128 = 100352 >= N_NODES
#define NPAD 100352
#define BSH 7
#define BMASK 127
#define CAP 4096  // static per-bucket capacity (mean 2040 -> safe)
#define MSTRIDE 36 // u32 stride of an LDS mean row (32 payload + 4 pad)

typedef float v2f __attribute__((ext_vector_type(2)));

__device__ inline void fma4(float a, const float4& w, float4& c) {
  c.x = fmaf(a, w.x, c.x);
  c.y = fmaf(a, w.y, c.y);
  c.z = fmaf(a, w.z, c.z);
  c.w = fmaf(a, w.w, c.w);
}
__device__ inline unsigned short f2bf(float f) {  // RNE f32->bf16
  unsigned u = __float_as_uint(f);
  u += 0x7fffu + ((u >> 16) & 1u);
  return (unsigned short)(u >> 16);
}
__device__ inline unsigned pack2bf(float a, float b) {
  return (unsigned)f2bf(a) | ((unsigned)f2bf(b) << 16);
}
__device__ inline unsigned packfp8x4(float a, float b, float c, float d) {
  int pk = __builtin_amdgcn_cvt_pk_fp8_f32(a, b, 0, false);
  pk = __builtin_amdgcn_cvt_pk_fp8_f32(c, d, pk, true);
  return (unsigned)pk;
}
// relu(bf16(m) + bf16(s)) for 4 packed bf16 elements (bit-identical f32 math)
__device__ inline float4 relu_mix(uint2 m, uint2 s) {
  float4 v;
  v.x = fmaxf(__uint_as_float(m.x << 16) + __uint_as_float(s.x << 16), 0.f);
  v.y = fmaxf(__uint_as_float(m.x & 0xffff0000u) +
                  __uint_as_float(s.x & 0xffff0000u), 0.f);
  v.z = fmaxf(__uint_as_float(m.y << 16) + __uint_as_float(s.y << 16), 0.f);
  v.w = fmaxf(__uint_as_float(m.y & 0xffff0000u) +
                  __uint_as_float(s.y & 0xffff0000u), 0.f);
  return v;
}
// accumulate 16 fp8-decoded floats from a uint4 (zeros decode to 0.0f)
__device__ inline void acc16(const uint4& u, float* acc) {
  v2f f0 = __builtin_amdgcn_cvt_pk_f32_fp8((int)u.x, false);
  v2f f1 = __builtin_amdgcn_cvt_pk_f32_fp8((int)u.x, true);
  v2f f2 = __builtin_amdgcn_cvt_pk_f32_fp8((int)u.y, false);
  v2f f3 = __builtin_amdgcn_cvt_pk_f32_fp8((int)u.y, true);
  v2f f4 = __builtin_amdgcn_cvt_pk_f32_fp8((int)u.z, false);
  v2f f5 = __builtin_amdgcn_cvt_pk_f32_fp8((int)u.z, true);
  v2f f6 = __builtin_amdgcn_cvt_pk_f32_fp8((int)u.w, false);
  v2f f7 = __builtin_amdgcn_cvt_pk_f32_fp8((int)u.w, true);
  acc[0] += f0[0];  acc[1] += f0[1];
  acc[2] += f1[0];  acc[3] += f1[1];
  acc[4] += f2[0];  acc[5] += f2[1];
  acc[6] += f3[0];  acc[7] += f3[1];
  acc[8] += f4[0];  acc[9] += f4[1];
  acc[10] += f5[0]; acc[11] += f5[1];
  acc[12] += f6[0]; acc[13] += f6[1];
  acc[14] += f7[0]; acc[15] += f7[1];
}

#define EPB 8192   // edges per scatter block (R17 proven)
#define EPT 32     // edges per thread (256 threads)
#define GB1 1563   // ceil(100000/64)

// ---------------------------------------------------------------------------
// R17 fusedA (FROZEN at R4 best): blocks [0,NSB) = scatter-only; blocks
// [NSB, NSB+GB1) = layer-1 dual-GEMM.
// ---------------------------------------------------------------------------
__global__ __launch_bounds__(256) void fusedA_k(
    const int* __restrict__ src, const int* __restrict__ dst,
    unsigned* __restrict__ bcur, unsigned* __restrict__ ep,
    const float* __restrict__ x, const float* __restrict__ W1n,
    const float* __restrict__ W1s, const float* __restrict__ b1,
    unsigned* __restrict__ xnb8, unsigned short* __restrict__ xsb,
    int E, int NSB, int M) {
  __shared__ __align__(16) float smem[8192];  // 32768 B
  const int tid = threadIdx.x;

  if ((int)blockIdx.x < NSB) {
    // ---------------- scatter body ----------------
    unsigned* lh = (unsigned*)smem;
    unsigned* lbase = lh + NB;
    for (int i = tid; i < NB; i += 256) lh[i] = 0;
    __syncthreads();
    const int ebase = blockIdx.x * EPB;
    unsigned rb[EPT];  // (rank<<10) | bucket
#pragma unroll
    for (int it = 0; it < EPT; ++it) {
      int e = ebase + it * 256 + tid;
      if (e < E) {
        unsigned b = ((unsigned)dst[e]) >> BSH;
        unsigned r = atomicAdd(&lh[b], 1u);  // r < 8192 -> fits in 22 bits
        rb[it] = (r << 10) | b;
      }
    }
    __syncthreads();
    for (int i = tid; i < NB; i += 256)
      lbase[i] = lh[i] ? atomicAdd(&bcur[i], lh[i]) : 0u;
    __syncthreads();
#pragma unroll
    for (int it = 0; it < EPT; ++it) {
      int e = ebase + it * 256 + tid;
      if (e < E) {
        unsigned b = rb[it] & 1023u;
        unsigned r = rb[it] >> 10;
        ep[(size_t)b * CAP + lbase[b] + r] =
            (((unsigned)src[e]) << BSH) | (((unsigned)dst[e]) & BMASK);
      }
    }
    return;
  }

  // ---------------- gemm1 body ----------------
  float* Wn = smem;
  float* Ws = smem + 4096;
  const int row0 = ((int)blockIdx.x - NSB) * 64;

  for (int i = tid; i < 1024; i += 256) {
    ((float4*)Wn)[i] = ((const float4*)W1n)[i];
    ((float4*)Ws)[i] = ((const float4*)W1s)[i];
  }

  const int tx = tid & 15;
  const int ty = tid >> 4;
  const int arow = ty * 4;

  const float* xr[4];
#pragma unroll
  for (int r = 0; r < 4; ++r) {
    long long gr = row0 + arow + r;
    if (gr >= M) gr = M - 1;
    xr[r] = x + gr * 64;
  }

  float4 an[4], as[4];
#pragma unroll
  for (int r = 0; r < 4; ++r) {
    an[r] = make_float4(0.f, 0.f, 0.f, 0.f);
    as[r] = make_float4(0.f, 0.f, 0.f, 0.f);
  }
  __syncthreads();

#pragma unroll 2
  for (int k4 = 0; k4 < 16; ++k4) {
    float4 a[4];
#pragma unroll
    for (int r = 0; r < 4; ++r) a[r] = *(const float4*)(xr[r] + 4 * k4);
    float4 wn0 = *(const float4*)&Wn[(4 * k4 + 0) * 64 + 4 * tx];
    float4 wn1 = *(const float4*)&Wn[(4 * k4 + 1) * 64 + 4 * tx];
    float4 wn2 = *(const float4*)&Wn[(4 * k4 + 2) * 64 + 4 * tx];
    float4 wn3 = *(const float4*)&Wn[(4 * k4 + 3) * 64 + 4 * tx];
    float4 ws0 = *(const float4*)&Ws[(4 * k4 + 0) * 64 + 4 * tx];
    float4 ws1 = *(const float4*)&Ws[(4 * k4 + 1) * 64 + 4 * tx];
    float4 ws2 = *(const float4*)&Ws[(4 * k4 + 2) * 64 + 4 * tx];
    float4 ws3 = *(const float4*)&Ws[(4 * k4 + 3) * 64 + 4 * tx];
#pragma unroll
    for (int r = 0; r < 4; ++r) {
      fma4(a[r].x, wn0, an[r]);
      fma4(a[r].y, wn1, an[r]);
      fma4(a[r].z, wn2, an[r]);
      fma4(a[r].w, wn3, an[r]);
      fma4(a[r].x, ws0, as[r]);
      fma4(a[r].y, ws1, as[r]);
      fma4(a[r].z, ws2, as[r]);
      fma4(a[r].w, ws3, as[r]);
    }
  }

  const float4 bv = *(const float4*)&b1[4 * tx];
#pragma unroll
  for (int r = 0; r < 4; ++r) {
    int row = row0 + arow + r;
    if (row < M) {
      ushort4 ps;
      ps.x = f2bf(as[r].x + bv.x);
      ps.y = f2bf(as[r].y + bv.y);
      ps.z = f2bf(as[r].z + bv.z);
      ps.w = f2bf(as[r].w + bv.w);
      *(ushort4*)&xsb[(long long)row * 64 + 4 * tx] = ps;
      xnb8[(size_t)row * 16 + tx] =
          packfp8x4(an[r].x, an[r].y, an[r].z, an[r].w);
    }
  }
}

// ---------------------------------------------------------------------------
// bsort (FROZEN): per-bucket counting sort -> per-node contiguous src runs.
// ---------------------------------------------------------------------------
__global__ __launch_bounds__(256) void bsort_k(const unsigned* __restrict__ ep,
                                               const unsigned* __restrict__ bcur,
                                               int* __restrict__ ssrc,
                                               uint2* __restrict__ rows2) {
  __shared__ unsigned cnt[128];
  __shared__ unsigned sc[128];
  const int tid = threadIdx.x;
  const int b = blockIdx.x;
  const unsigned cntb = bcur[b];
  const unsigned beg = (unsigned)(b * CAP);
  if (tid < 128) cnt[tid] = 0;
  __syncthreads();
  for (unsigned j = tid; j < cntb; j += 256)
    atomicAdd(&cnt[ep[(size_t)beg + j] & BMASK], 1u);
  __syncthreads();
  unsigned v = (tid < 128) ? cnt[tid] : 0u;
  if (tid < 128) sc[tid] = v;
  __syncthreads();
  for (int off = 1; off < 128; off <<= 1) {
    unsigned t = (tid < 128 && tid >= off) ? sc[tid - off] : 0u;
    __syncthreads();
    if (tid < 128) sc[tid] += t;
    __syncthreads();
  }
  if (tid < 128) {
    unsigned ex = sc[tid] - v;
    rows2[b * 128 + tid] = make_uint2(beg + ex, beg + ex + v);
    cnt[tid] = ex;
  }
  __syncthreads();
  for (unsigned j = tid; j < cntb; j += 256) {
    unsigned p = ep[(size_t)beg + j];
    unsigned r = atomicAdd(&cnt[p & BMASK], 1u);
    ssrc[(size_t)beg + r] = (int)(p >> BSH);
  }
}

// ---------------------------------------------------------------------------
// R20 fgg: fused gather1 + gemm2 per 64 nodes. NEW vs R4:
//  (1) block-local degree-sorted processing order (waves serve similar-degree
//      nodes -> less wave-max-degree issue waste);
//  (2) predicated-zero tail loads (no clamped duplicate line-requests;
//      fp8 0x00 -> 0.0f so the w-mask disappears; bit-identical).
// ---------------------------------------------------------------------------
__global__ __launch_bounds__(256) void fgg_k(
    const uint4* __restrict__ valb4, const int* __restrict__ ssrc,
    const uint2* __restrict__ rows2, const unsigned short* __restrict__ xsb,
    const float* __restrict__ W2n, const float* __restrict__ W2s,
    const float* __restrict__ b2, unsigned* __restrict__ hnb8,
    float* __restrict__ hs, int M) {
  __shared__ float Wn[64 * 32];
  __shared__ float Ws[64 * 32];
  __shared__ unsigned mlds[64 * MSTRIDE];  // 9216 B
  __shared__ unsigned degs[64];
  __shared__ unsigned begs[64];
  __shared__ unsigned char perm[64];
  const int tid = threadIdx.x;
  const int node0 = blockIdx.x * 64;

  for (int i = tid; i < 512; i += 256) {
    ((float4*)Wn)[i] = ((const float4*)W2n)[i];
    ((float4*)Ws)[i] = ((const float4*)W2s)[i];
  }

  // ---- block-local degree sort of the 64 nodes ----
  if (tid < 64) {
    uint2 be = rows2[node0 + tid];  // node < 100032 <= NPAD: always valid
    degs[tid] = be.y - be.x;
    begs[tid] = be.x;
  }
  __syncthreads();
  if (tid < 64) {
    unsigned d = degs[tid];
    int rank = 0;
    for (int j2 = 0; j2 < 64; ++j2) {
      unsigned dj = degs[j2];
      rank += (dj < d) || (dj == d && j2 < tid);
    }
    perm[rank] = (unsigned char)tid;
  }
  __syncthreads();

  // ---- gather phase: P=4 lanes per node, 16 cols each ----
  const int slot = tid >> 2;           // sorted slot 0..63
  const int lrow = perm[slot];         // true local row
  const int p = tid & 3;
  const unsigned dg = degs[lrow];
  const unsigned beg = begs[lrow];
  const unsigned end = beg + dg;

  float acc[16];
#pragma unroll
  for (int q = 0; q < 16; ++q) acc[q] = 0.f;

  unsigned j = beg;
  for (; j + 8 <= end; j += 8) {
    int sn[8];
#pragma unroll
    for (int i = 0; i < 8; ++i) sn[i] = ssrc[j + i];
    uint4 u[8];
#pragma unroll
    for (int i = 0; i < 8; ++i) u[i] = valb4[(size_t)sn[i] * 4 + p];
#pragma unroll
    for (int i = 0; i < 8; ++i) acc16(u[i], acc);
  }
  if (j < end) {
    uint4 u[8];
#pragma unroll
    for (int i = 0; i < 8; ++i) {
      u[i] = make_uint4(0u, 0u, 0u, 0u);
      if (j + i < end) {
        int s = ssrc[j + i];
        u[i] = valb4[(size_t)s * 4 + p];
      }
    }
#pragma unroll
    for (int i = 0; i < 8; ++i) acc16(u[i], acc);
  }

  const float inv = dg ? 1.f / (float)dg : 0.f;
  uint4 pk0, pk1;
  pk0.x = pack2bf(acc[0] * inv, acc[1] * inv);
  pk0.y = pack2bf(acc[2] * inv, acc[3] * inv);
  pk0.z = pack2bf(acc[4] * inv, acc[5] * inv);
  pk0.w = pack2bf(acc[6] * inv, acc[7] * inv);
  pk1.x = pack2bf(acc[8] * inv, acc[9] * inv);
  pk1.y = pack2bf(acc[10] * inv, acc[11] * inv);
  pk1.z = pack2bf(acc[12] * inv, acc[13] * inv);
  pk1.w = pack2bf(acc[14] * inv, acc[15] * inv);
  *(uint4*)&mlds[lrow * MSTRIDE + p * 8] = pk0;
  *(uint4*)&mlds[lrow * MSTRIDE + p * 8 + 4] = pk1;
  __syncthreads();

  // ---- GEMM phase: 64 rows x dual 32 cols (by true local row) ----
  const int tx = tid & 7;
  const int ty = tid >> 3;  // 0..31
  const int arow = ty * 2;

  const uint2* mp[2];
  const uint2* sp[2];
#pragma unroll
  for (int r = 0; r < 2; ++r) {
    long long gr = node0 + arow + r;
    if (gr >= M) gr = M - 1;
    mp[r] = (const uint2*)&mlds[(arow + r) * MSTRIDE];
    sp[r] = (const uint2*)(xsb + gr * 64);
  }

  float4 an[2], as[2];
#pragma unroll
  for (int r = 0; r < 2; ++r) {
    an[r] = make_float4(0.f, 0.f, 0.f, 0.f);
    as[r] = make_float4(0.f, 0.f, 0.f, 0.f);
  }

#pragma unroll 2
  for (int k4 = 0; k4 < 16; ++k4) {
    float4 a[2];
#pragma unroll
    for (int r = 0; r < 2; ++r) a[r] = relu_mix(mp[r][k4], sp[r][k4]);
    float4 wn0 = *(const float4*)&Wn[(4 * k4 + 0) * 32 + 4 * tx];
    float4 wn1 = *(const float4*)&Wn[(4 * k4 + 1) * 32 + 4 * tx];
    float4 wn2 = *(const float4*)&Wn[(4 * k4 + 2) * 32 + 4 * tx];
    float4 wn3 = *(const float4*)&Wn[(4 * k4 + 3) * 32 + 4 * tx];
    float4 ws0 = *(const float4*)&Ws[(4 * k4 + 0) * 32 + 4 * tx];
    float4 ws1 = *(const float4*)&Ws[(4 * k4 + 1) * 32 + 4 * tx];
    float4 ws2 = *(const float4*)&Ws[(4 * k4 + 2) * 32 + 4 * tx];
    float4 ws3 = *(const float4*)&Ws[(4 * k4 + 3) * 32 + 4 * tx];
#pragma unroll
    for (int r = 0; r < 2; ++r) {
      fma4(a[r].x, wn0, an[r]);
      fma4(a[r].y, wn1, an[r]);
      fma4(a[r].z, wn2, an[r]);
      fma4(a[r].w, wn3, an[r]);
      fma4(a[r].x, ws0, as[r]);
      fma4(a[r].y, ws1, as[r]);
      fma4(a[r].z, ws2, as[r]);
      fma4(a[r].w, ws3, as[r]);
    }
  }

  const float4 bv = *(const float4*)&b2[4 * tx];
#pragma unroll
  for (int r = 0; r < 2; ++r) {
    int row = node0 + arow + r;
    if (row < M) {
      float4 o;
      o.x = as[r].x + bv.x;
      o.y = as[r].y + bv.y;
      o.z = as[r].z + bv.z;
      o.w = as[r].w + bv.w;
      *(float4*)&hs[(long long)row * 32 + 4 * tx] = o;
      hnb8[(size_t)row * 8 + tx] =
          packfp8x4(an[r].x, an[r].y, an[r].z, an[r].w);
    }
  }
}

// ---------------------------------------------------------------------------
// R20 gather2: out[node] = mean_j fp8decode(hnb8[ssrc[j]]) + hs[node].
// Same two changes: local degree sort (128 nodes) + predicated-zero tail.
// ---------------------------------------------------------------------------
__global__ __launch_bounds__(256) void gather2_k(
    const uint4* __restrict__ valb4, const int* __restrict__ ssrc,
    const uint2* __restrict__ rows2, const float* __restrict__ base,
    float* __restrict__ out, int N) {
  __shared__ unsigned degs[128];
  __shared__ unsigned begs[128];
  __shared__ unsigned char perm[128];
  const int tid = threadIdx.x;
  const int node0 = blockIdx.x * 128;

  if (tid < 128) {
    uint2 be = rows2[node0 + tid];  // node < 100352 = NPAD: always valid
    degs[tid] = be.y - be.x;
    begs[tid] = be.x;
  }
  __syncthreads();
  if (tid < 128) {
    unsigned d = degs[tid];
    int rank = 0;
    for (int j2 = 0; j2 < 128; ++j2) {
      unsigned dj = degs[j2];
      rank += (dj < d) || (dj == d && j2 < tid);
    }
    perm[rank] = (unsigned char)tid;
  }
  __syncthreads();

  const int slot = tid >> 1;
  const int lrow = perm[slot];
  const int node = node0 + lrow;
  const int p = tid & 1;
  const unsigned dg = degs[lrow];
  const unsigned beg = begs[lrow];
  const unsigned end = beg + dg;

  float acc[16];
#pragma unroll
  for (int q = 0; q < 16; ++q) acc[q] = 0.f;

  unsigned j = beg;
  for (; j + 8 <= end; j += 8) {
    int sn[8];
#pragma unroll
    for (int i = 0; i < 8; ++i) sn[i] = ssrc[j + i];
    uint4 u[8];
#pragma unroll
    for (int i = 0; i < 8; ++i) u[i] = valb4[(size_t)sn[i] * 2 + p];
#pragma unroll
    for (int i = 0; i < 8; ++i) acc16(u[i], acc);
  }
  if (j < end) {
    uint4 u[8];
#pragma unroll
    for (int i = 0; i < 8; ++i) {
      u[i] = make_uint4(0u, 0u, 0u, 0u);
      if (j + i < end) {
        int s = ssrc[j + i];
        u[i] = valb4[(size_t)s * 2 + p];
      }
    }
#pragma unroll
    for (int i = 0; i < 8; ++i) acc16(u[i], acc);
  }

  if (node < N) {
    const float inv = dg ? 1.f / (float)dg : 0.f;
    const size_t o = (size_t)node * 32 + 16 * p;
#pragma unroll
    for (int q4 = 0; q4 < 4; ++q4) {
      float4 bv = *(const float4*)&base[o + 4 * q4];
      float4 ov;
      ov.x = acc[4 * q4 + 0] * inv + bv.x;
      ov.y = acc[4 * q4 + 1] * inv + bv.y;
      ov.z = acc[4 * q4 + 2] * inv + bv.z;
      ov.w = acc[4 * q4 + 3] * inv + bv.w;
      *(float4*)&out[o + 4 * q4] = ov;
    }
  }
}

extern "C" void kernel_launch(void* const* d_in, const int* in_sizes, int n_in,
                              void* d_out, int out_size, void* d_ws,
                              size_t ws_size, hipStream_t stream) {
  const float* x   = (const float*)d_in[0];
  const int*   ei  = (const int*)d_in[1];  // [2, E]: row0 = src, row1 = dst
  const float* W1n = (const float*)d_in[2];
  const float* W1s = (const float*)d_in[3];
  const float* b1  = (const float*)d_in[4];
  const float* W2n = (const float*)d_in[5];
  const float* W2s = (const float*)d_in[6];
  const float* b2  = (const float*)d_in[7];
  float* out = (float*)d_out;

  const int E = in_sizes[1] / 2;  // 1,600,000
  const int M = N_NODES;
  const int* src = ei;
  const int* dst = ei + E;
  const int NSB = (E + EPB - 1) / EPB;  // 196

  // Workspace layout (bytes):
  //   ep    @ 0           12,845,056  (NB*CAP u32; hnb8 aliases after bsort)
  //   ssrc  @ 12,845,056  12,845,056
  //   rows2 @ 25,690,112     802,816
  //   bcur  @ 26,492,928       3,136
  //   xnb8  @ 26,496,064   6,400,000  (fp8 M x 64)
  //   xsb   @ 32,896,064  12,800,000  (bf16 M x 64)
  //   hs    @ 45,696,064  12,800,000  (f32 M x 32)
  char* wsb = (char*)d_ws;
  unsigned*       ep    = (unsigned*)(wsb);
  int*            ssrc  = (int*)(wsb + 12845056);
  uint2*          rows2 = (uint2*)(wsb + 25690112);
  unsigned*       bcur  = (unsigned*)(wsb + 26492928);
  unsigned*       xnb8  = (unsigned*)(wsb + 26496064);
  unsigned short* xsb   = (unsigned short*)(wsb + 32896064);
  float*          hs    = (float*)(wsb + 45696064);
  unsigned*       hnb8  = (unsigned*)(wsb);  // aliases ep (dead after bsort)

  // 1) zero bucket cursors (3 KB)
  hipMemsetAsync(bcur, 0, NB * 4, stream);
  // 2) fusedA: 196-block edge scatter overlapped with layer-1 dual-GEMM
  fusedA_k<<<NSB + GB1, 256, 0, stream>>>(src, dst, bcur, ep, x, W1n, W1s, b1,
                                          xnb8, xsb, E, NSB, M);
  // 3) per-bucket counting sort -> ssrc runs + rows2
  bsort_k<<<NB, 256, 0, stream>>>(ep, bcur, ssrc, rows2);
  // 4) fused gather1 + gemm2 (degree-sorted, predicated tails)
  fgg_k<<<GB1, 256, 0, stream>>>((const uint4*)xnb8, ssrc, rows2, xsb, W2n,
                                 W2s, b2, hnb8, hs, M);
  // 5) out = mean(fp8(hn)[src]) + hs (degree-sorted, predicated tails)
  gather2_k<<<(M + 127) / 128, 256, 0, stream>>>((const uint4*)hnb8, ssrc,
                                                 rows2, hs, out, M);
}

// Round 8
// 211.780 us; speedup vs baseline: 2.5656x; 1.0206x over previous
//
#include <hip/hip_runtime.h>
#include <hip/hip_bf16.h>

#define N_NODES 100000
#define NB 784   // buckets of 128 nodes: 784*128 = 100352 >= N_NODES
#define NPAD 100352
#define BSH 7
#define BMASK 127
#define CAP 4096  // static per-bucket capacity (mean 2040 -> safe)
#define MSTRIDE 36 // u32 stride of an LDS mean row (32 payload + 4 pad)
#define SCAP 3072  // LDS ssrc-span capacity (bucket cnt ~2040 +- 45; max<2300)

typedef float v2f __attribute__((ext_vector_type(2)));

__device__ inline void fma4(float a, const float4& w, float4& c) {
  c.x = fmaf(a, w.x, c.x);
  c.y = fmaf(a, w.y, c.y);
  c.z = fmaf(a, w.z, c.z);
  c.w = fmaf(a, w.w, c.w);
}
__device__ inline unsigned short f2bf(float f) {  // RNE f32->bf16
  unsigned u = __float_as_uint(f);
  u += 0x7fffu + ((u >> 16) & 1u);
  return (unsigned short)(u >> 16);
}
__device__ inline unsigned pack2bf(float a, float b) {
  return (unsigned)f2bf(a) | ((unsigned)f2bf(b) << 16);
}
__device__ inline unsigned packfp8x4(float a, float b, float c, float d) {
  int pk = __builtin_amdgcn_cvt_pk_fp8_f32(a, b, 0, false);
  pk = __builtin_amdgcn_cvt_pk_fp8_f32(c, d, pk, true);
  return (unsigned)pk;
}
// relu(bf16(m) + bf16(s)) for 4 packed bf16 elements (bit-identical f32 math)
__device__ inline float4 relu_mix(uint2 m, uint2 s) {
  float4 v;
  v.x = fmaxf(__uint_as_float(m.x << 16) + __uint_as_float(s.x << 16), 0.f);
  v.y = fmaxf(__uint_as_float(m.x & 0xffff0000u) +
                  __uint_as_float(s.x & 0xffff0000u), 0.f);
  v.z = fmaxf(__uint_as_float(m.y << 16) + __uint_as_float(s.y << 16), 0.f);
  v.w = fmaxf(__uint_as_float(m.y & 0xffff0000u) +
                  __uint_as_float(s.y & 0xffff0000u), 0.f);
  return v;
}
// accumulate 16 fp8-decoded floats from a uint4
__device__ inline void acc16(const uint4& u, float* acc) {
  v2f f0 = __builtin_amdgcn_cvt_pk_f32_fp8((int)u.x, false);
  v2f f1 = __builtin_amdgcn_cvt_pk_f32_fp8((int)u.x, true);
  v2f f2 = __builtin_amdgcn_cvt_pk_f32_fp8((int)u.y, false);
  v2f f3 = __builtin_amdgcn_cvt_pk_f32_fp8((int)u.y, true);
  v2f f4 = __builtin_amdgcn_cvt_pk_f32_fp8((int)u.z, false);
  v2f f5 = __builtin_amdgcn_cvt_pk_f32_fp8((int)u.z, true);
  v2f f6 = __builtin_amdgcn_cvt_pk_f32_fp8((int)u.w, false);
  v2f f7 = __builtin_amdgcn_cvt_pk_f32_fp8((int)u.w, true);
  acc[0] += f0[0];  acc[1] += f0[1];
  acc[2] += f1[0];  acc[3] += f1[1];
  acc[4] += f2[0];  acc[5] += f2[1];
  acc[6] += f3[0];  acc[7] += f3[1];
  acc[8] += f4[0];  acc[9] += f4[1];
  acc[10] += f5[0]; acc[11] += f5[1];
  acc[12] += f6[0]; acc[13] += f6[1];
  acc[14] += f7[0]; acc[15] += f7[1];
}
// masked accumulate (w in {0,1}; fmaf(1,f,a) == a+f bit-identically)
__device__ inline void macc16(const uint4& u, float w, float* acc) {
  v2f f0 = __builtin_amdgcn_cvt_pk_f32_fp8((int)u.x, false);
  v2f f1 = __builtin_amdgcn_cvt_pk_f32_fp8((int)u.x, true);
  v2f f2 = __builtin_amdgcn_cvt_pk_f32_fp8((int)u.y, false);
  v2f f3 = __builtin_amdgcn_cvt_pk_f32_fp8((int)u.y, true);
  v2f f4 = __builtin_amdgcn_cvt_pk_f32_fp8((int)u.z, false);
  v2f f5 = __builtin_amdgcn_cvt_pk_f32_fp8((int)u.z, true);
  v2f f6 = __builtin_amdgcn_cvt_pk_f32_fp8((int)u.w, false);
  v2f f7 = __builtin_amdgcn_cvt_pk_f32_fp8((int)u.w, true);
  acc[0] = fmaf(w, f0[0], acc[0]);   acc[1] = fmaf(w, f0[1], acc[1]);
  acc[2] = fmaf(w, f1[0], acc[2]);   acc[3] = fmaf(w, f1[1], acc[3]);
  acc[4] = fmaf(w, f2[0], acc[4]);   acc[5] = fmaf(w, f2[1], acc[5]);
  acc[6] = fmaf(w, f3[0], acc[6]);   acc[7] = fmaf(w, f3[1], acc[7]);
  acc[8] = fmaf(w, f4[0], acc[8]);   acc[9] = fmaf(w, f4[1], acc[9]);
  acc[10] = fmaf(w, f5[0], acc[10]); acc[11] = fmaf(w, f5[1], acc[11]);
  acc[12] = fmaf(w, f6[0], acc[12]); acc[13] = fmaf(w, f6[1], acc[13]);
  acc[14] = fmaf(w, f7[0], acc[14]); acc[15] = fmaf(w, f7[1], acc[15]);
}

#define EPB 8192   // edges per scatter block (R17 proven)
#define EPT 32     // edges per thread (256 threads)
#define GB1 1563   // ceil(100000/64)

// ---------------------------------------------------------------------------
// fusedA (FROZEN at R4 best): blocks [0,NSB) = scatter-only; blocks
// [NSB, NSB+GB1) = layer-1 dual-GEMM.
// ---------------------------------------------------------------------------
__global__ __launch_bounds__(256) void fusedA_k(
    const int* __restrict__ src, const int* __restrict__ dst,
    unsigned* __restrict__ bcur, unsigned* __restrict__ ep,
    const float* __restrict__ x, const float* __restrict__ W1n,
    const float* __restrict__ W1s, const float* __restrict__ b1,
    unsigned* __restrict__ xnb8, unsigned short* __restrict__ xsb,
    int E, int NSB, int M) {
  __shared__ __align__(16) float smem[8192];  // 32768 B
  const int tid = threadIdx.x;

  if ((int)blockIdx.x < NSB) {
    // ---------------- scatter body ----------------
    unsigned* lh = (unsigned*)smem;
    unsigned* lbase = lh + NB;
    for (int i = tid; i < NB; i += 256) lh[i] = 0;
    __syncthreads();
    const int ebase = blockIdx.x * EPB;
    unsigned rb[EPT];  // (rank<<10) | bucket
#pragma unroll
    for (int it = 0; it < EPT; ++it) {
      int e = ebase + it * 256 + tid;
      if (e < E) {
        unsigned b = ((unsigned)dst[e]) >> BSH;
        unsigned r = atomicAdd(&lh[b], 1u);  // r < 8192 -> fits in 22 bits
        rb[it] = (r << 10) | b;
      }
    }
    __syncthreads();
    for (int i = tid; i < NB; i += 256)
      lbase[i] = lh[i] ? atomicAdd(&bcur[i], lh[i]) : 0u;
    __syncthreads();
#pragma unroll
    for (int it = 0; it < EPT; ++it) {
      int e = ebase + it * 256 + tid;
      if (e < E) {
        unsigned b = rb[it] & 1023u;
        unsigned r = rb[it] >> 10;
        ep[(size_t)b * CAP + lbase[b] + r] =
            (((unsigned)src[e]) << BSH) | (((unsigned)dst[e]) & BMASK);
      }
    }
    return;
  }

  // ---------------- gemm1 body ----------------
  float* Wn = smem;
  float* Ws = smem + 4096;
  const int row0 = ((int)blockIdx.x - NSB) * 64;

  for (int i = tid; i < 1024; i += 256) {
    ((float4*)Wn)[i] = ((const float4*)W1n)[i];
    ((float4*)Ws)[i] = ((const float4*)W1s)[i];
  }

  const int tx = tid & 15;
  const int ty = tid >> 4;
  const int arow = ty * 4;

  const float* xr[4];
#pragma unroll
  for (int r = 0; r < 4; ++r) {
    long long gr = row0 + arow + r;
    if (gr >= M) gr = M - 1;
    xr[r] = x + gr * 64;
  }

  float4 an[4], as[4];
#pragma unroll
  for (int r = 0; r < 4; ++r) {
    an[r] = make_float4(0.f, 0.f, 0.f, 0.f);
    as[r] = make_float4(0.f, 0.f, 0.f, 0.f);
  }
  __syncthreads();

#pragma unroll 2
  for (int k4 = 0; k4 < 16; ++k4) {
    float4 a[4];
#pragma unroll
    for (int r = 0; r < 4; ++r) a[r] = *(const float4*)(xr[r] + 4 * k4);
    float4 wn0 = *(const float4*)&Wn[(4 * k4 + 0) * 64 + 4 * tx];
    float4 wn1 = *(const float4*)&Wn[(4 * k4 + 1) * 64 + 4 * tx];
    float4 wn2 = *(const float4*)&Wn[(4 * k4 + 2) * 64 + 4 * tx];
    float4 wn3 = *(const float4*)&Wn[(4 * k4 + 3) * 64 + 4 * tx];
    float4 ws0 = *(const float4*)&Ws[(4 * k4 + 0) * 64 + 4 * tx];
    float4 ws1 = *(const float4*)&Ws[(4 * k4 + 1) * 64 + 4 * tx];
    float4 ws2 = *(const float4*)&Ws[(4 * k4 + 2) * 64 + 4 * tx];
    float4 ws3 = *(const float4*)&Ws[(4 * k4 + 3) * 64 + 4 * tx];
#pragma unroll
    for (int r = 0; r < 4; ++r) {
      fma4(a[r].x, wn0, an[r]);
      fma4(a[r].y, wn1, an[r]);
      fma4(a[r].z, wn2, an[r]);
      fma4(a[r].w, wn3, an[r]);
      fma4(a[r].x, ws0, as[r]);
      fma4(a[r].y, ws1, as[r]);
      fma4(a[r].z, ws2, as[r]);
      fma4(a[r].w, ws3, as[r]);
    }
  }

  const float4 bv = *(const float4*)&b1[4 * tx];
#pragma unroll
  for (int r = 0; r < 4; ++r) {
    int row = row0 + arow + r;
    if (row < M) {
      ushort4 ps;
      ps.x = f2bf(as[r].x + bv.x);
      ps.y = f2bf(as[r].y + bv.y);
      ps.z = f2bf(as[r].z + bv.z);
      ps.w = f2bf(as[r].w + bv.w);
      *(ushort4*)&xsb[(long long)row * 64 + 4 * tx] = ps;
      xnb8[(size_t)row * 16 + tx] =
          packfp8x4(an[r].x, an[r].y, an[r].z, an[r].w);
    }
  }
}

// ---------------------------------------------------------------------------
// bsort (FROZEN): per-bucket counting sort -> per-node contiguous src runs.
// ---------------------------------------------------------------------------
__global__ __launch_bounds__(256) void bsort_k(const unsigned* __restrict__ ep,
                                               const unsigned* __restrict__ bcur,
                                               int* __restrict__ ssrc,
                                               uint2* __restrict__ rows2) {
  __shared__ unsigned cnt[128];
  __shared__ unsigned sc[128];
  const int tid = threadIdx.x;
  const int b = blockIdx.x;
  const unsigned cntb = bcur[b];
  const unsigned beg = (unsigned)(b * CAP);
  if (tid < 128) cnt[tid] = 0;
  __syncthreads();
  for (unsigned j = tid; j < cntb; j += 256)
    atomicAdd(&cnt[ep[(size_t)beg + j] & BMASK], 1u);
  __syncthreads();
  unsigned v = (tid < 128) ? cnt[tid] : 0u;
  if (tid < 128) sc[tid] = v;
  __syncthreads();
  for (int off = 1; off < 128; off <<= 1) {
    unsigned t = (tid < 128 && tid >= off) ? sc[tid - off] : 0u;
    __syncthreads();
    if (tid < 128) sc[tid] += t;
    __syncthreads();
  }
  if (tid < 128) {
    unsigned ex = sc[tid] - v;
    rows2[b * 128 + tid] = make_uint2(beg + ex, beg + ex + v);
    cnt[tid] = ex;
  }
  __syncthreads();
  for (unsigned j = tid; j < cntb; j += 256) {
    unsigned p = ep[(size_t)beg + j];
    unsigned r = atomicAdd(&cnt[p & BMASK], 1u);
    ssrc[(size_t)beg + r] = (int)(p >> BSH);
  }
}

// ---------------------------------------------------------------------------
// R21 fgg: fused gather1 + gemm2 per 64 nodes. vs R4:
//  (1) block's ssrc span (contiguous: runs ordered by node-in-bucket, block =
//      half bucket) staged once into LDS, coalesced -> removes the ssrc L2
//      hop from the gather's dependent chain (ssrc->table was 2-hop serial);
//  (2) W2n/W2s read directly from L1 in the GEMM loop (8 KB broadcast
//      tables; same insight as R14's A-stage drop) -> LDS 26->21.5 KB,
//      5 -> 7 blocks/CU.
// Gather arithmetic identical to R4 (clamped-dup tail + w-masked fmaf).
// ---------------------------------------------------------------------------
__global__ __launch_bounds__(256) void fgg_k(
    const uint4* __restrict__ valb4, const int* __restrict__ ssrc,
    const uint2* __restrict__ rows2, const unsigned short* __restrict__ xsb,
    const float* __restrict__ W2n, const float* __restrict__ W2s,
    const float* __restrict__ b2, unsigned* __restrict__ hnb8,
    float* __restrict__ hs, int M) {
  __shared__ unsigned mlds[64 * MSTRIDE];  // 9216 B
  __shared__ int ssrc_l[SCAP];             // 12288 B
  const int tid = threadIdx.x;
  const int node0 = blockIdx.x * 64;

  // ---- stage the block's contiguous ssrc span ----
  const unsigned span_beg = rows2[node0].x;           // broadcast load
  const unsigned span_end = rows2[node0 + 63].y;      // broadcast load
  const unsigned span_n = span_end - span_beg;
  const bool fits = (span_n <= (unsigned)SCAP);
  if (fits)
    for (unsigned i = tid; i < span_n; i += 256) ssrc_l[i] = ssrc[span_beg + i];

  // ---- gather phase: P=4 lanes per node, 16 cols each ----
  constexpr int P = 4;
  const int lrow = tid / P;            // 0..63
  const int node = node0 + lrow;       // < 100032 <= NPAD, rows2 always valid
  const int p = tid & 3;
  const uint2 be = rows2[node];
  const unsigned beg = be.x, end = be.y;  // deg-0 -> beg==end
  __syncthreads();

  float acc[16];
#pragma unroll
  for (int q = 0; q < 16; ++q) acc[q] = 0.f;

  if (fits) {
    const unsigned lb = span_beg;
    unsigned j = beg;
    for (; j + 8 <= end; j += 8) {
      int sn[8];
#pragma unroll
      for (int i = 0; i < 8; ++i) sn[i] = ssrc_l[j - lb + i];
      uint4 u[8];
#pragma unroll
      for (int i = 0; i < 8; ++i) u[i] = valb4[(size_t)sn[i] * P + p];
#pragma unroll
      for (int i = 0; i < 8; ++i) acc16(u[i], acc);
    }
    if (j < end) {
      const unsigned last = end - 1;
      int sn[8];
#pragma unroll
      for (int i = 0; i < 8; ++i) {
        unsigned jj = j + i;
        sn[i] = ssrc_l[(jj < last ? jj : last) - lb];
      }
      uint4 u[8];
#pragma unroll
      for (int i = 0; i < 8; ++i) u[i] = valb4[(size_t)sn[i] * P + p];
#pragma unroll
      for (int i = 0; i < 8; ++i) macc16(u[i], ((j + i) < end) ? 1.f : 0.f, acc);
    }
  } else {
    unsigned j = beg;
    for (; j + 8 <= end; j += 8) {
      int sn[8];
#pragma unroll
      for (int i = 0; i < 8; ++i) sn[i] = ssrc[j + i];
      uint4 u[8];
#pragma unroll
      for (int i = 0; i < 8; ++i) u[i] = valb4[(size_t)sn[i] * P + p];
#pragma unroll
      for (int i = 0; i < 8; ++i) acc16(u[i], acc);
    }
    if (j < end) {
      const unsigned last = end - 1;
      int sn[8];
#pragma unroll
      for (int i = 0; i < 8; ++i) {
        unsigned jj = j + i;
        sn[i] = ssrc[jj < last ? jj : last];
      }
      uint4 u[8];
#pragma unroll
      for (int i = 0; i < 8; ++i) u[i] = valb4[(size_t)sn[i] * P + p];
#pragma unroll
      for (int i = 0; i < 8; ++i) macc16(u[i], ((j + i) < end) ? 1.f : 0.f, acc);
    }
  }

  const unsigned dg = end - beg;
  const float inv = dg ? 1.f / (float)dg : 0.f;
  uint4 pk0, pk1;
  pk0.x = pack2bf(acc[0] * inv, acc[1] * inv);
  pk0.y = pack2bf(acc[2] * inv, acc[3] * inv);
  pk0.z = pack2bf(acc[4] * inv, acc[5] * inv);
  pk0.w = pack2bf(acc[6] * inv, acc[7] * inv);
  pk1.x = pack2bf(acc[8] * inv, acc[9] * inv);
  pk1.y = pack2bf(acc[10] * inv, acc[11] * inv);
  pk1.z = pack2bf(acc[12] * inv, acc[13] * inv);
  pk1.w = pack2bf(acc[14] * inv, acc[15] * inv);
  *(uint4*)&mlds[lrow * MSTRIDE + p * 8] = pk0;
  *(uint4*)&mlds[lrow * MSTRIDE + p * 8 + 4] = pk1;
  __syncthreads();

  // ---- GEMM phase: 64 rows x dual 32 cols; W from L1 (broadcast) ----
  const int tx = tid & 7;
  const int ty = tid >> 3;  // 0..31
  const int arow = ty * 2;

  const uint2* mp[2];
  const uint2* sp[2];
#pragma unroll
  for (int r = 0; r < 2; ++r) {
    long long gr = node0 + arow + r;
    if (gr >= M) gr = M - 1;
    mp[r] = (const uint2*)&mlds[(arow + r) * MSTRIDE];
    sp[r] = (const uint2*)(xsb + gr * 64);
  }

  float4 an[2], as[2];
#pragma unroll
  for (int r = 0; r < 2; ++r) {
    an[r] = make_float4(0.f, 0.f, 0.f, 0.f);
    as[r] = make_float4(0.f, 0.f, 0.f, 0.f);
  }

#pragma unroll 2
  for (int k4 = 0; k4 < 16; ++k4) {
    float4 a[2];
#pragma unroll
    for (int r = 0; r < 2; ++r) a[r] = relu_mix(mp[r][k4], sp[r][k4]);
    float4 wn0 = *(const float4*)&W2n[(4 * k4 + 0) * 32 + 4 * tx];
    float4 wn1 = *(const float4*)&W2n[(4 * k4 + 1) * 32 + 4 * tx];
    float4 wn2 = *(const float4*)&W2n[(4 * k4 + 2) * 32 + 4 * tx];
    float4 wn3 = *(const float4*)&W2n[(4 * k4 + 3) * 32 + 4 * tx];
    float4 ws0 = *(const float4*)&W2s[(4 * k4 + 0) * 32 + 4 * tx];
    float4 ws1 = *(const float4*)&W2s[(4 * k4 + 1) * 32 + 4 * tx];
    float4 ws2 = *(const float4*)&W2s[(4 * k4 + 2) * 32 + 4 * tx];
    float4 ws3 = *(const float4*)&W2s[(4 * k4 + 3) * 32 + 4 * tx];
#pragma unroll
    for (int r = 0; r < 2; ++r) {
      fma4(a[r].x, wn0, an[r]);
      fma4(a[r].y, wn1, an[r]);
      fma4(a[r].z, wn2, an[r]);
      fma4(a[r].w, wn3, an[r]);
      fma4(a[r].x, ws0, as[r]);
      fma4(a[r].y, ws1, as[r]);
      fma4(a[r].z, ws2, as[r]);
      fma4(a[r].w, ws3, as[r]);
    }
  }

  const float4 bv = *(const float4*)&b2[4 * tx];
#pragma unroll
  for (int r = 0; r < 2; ++r) {
    int row = node0 + arow + r;
    if (row < M) {
      float4 o;
      o.x = as[r].x + bv.x;
      o.y = as[r].y + bv.y;
      o.z = as[r].z + bv.z;
      o.w = as[r].w + bv.w;
      *(float4*)&hs[(long long)row * 32 + 4 * tx] = o;
      hnb8[(size_t)row * 8 + tx] =
          packfp8x4(an[r].x, an[r].y, an[r].z, an[r].w);
    }
  }
}

// ---------------------------------------------------------------------------
// R21 gather2: out[node] = mean_j fp8decode(hnb8[ssrc[j]]) + hs[node].
// Block = 128 nodes = exactly one bucket -> ssrc span contiguous; staged
// into LDS like fgg. Gather arithmetic identical to R4.
// ---------------------------------------------------------------------------
__global__ __launch_bounds__(256) void gather2_k(
    const uint4* __restrict__ valb4, const int* __restrict__ ssrc,
    const uint2* __restrict__ rows2, const float* __restrict__ base,
    float* __restrict__ out, int N) {
  __shared__ int ssrc_l[SCAP];  // 12288 B
  const int tid = threadIdx.x;
  const int node0 = blockIdx.x * 128;

  const unsigned span_beg = rows2[node0].x;
  const unsigned span_end = rows2[node0 + 127].y;
  const unsigned span_n = span_end - span_beg;
  const bool fits = (span_n <= (unsigned)SCAP);
  if (fits)
    for (unsigned i = tid; i < span_n; i += 256) ssrc_l[i] = ssrc[span_beg + i];

  constexpr int P = 2;
  const int lrow = tid / P;
  const int node = node0 + lrow;   // < 100352 = NPAD: rows2 always valid
  const int p = tid & 1;
  const uint2 be = rows2[node];
  const unsigned beg = be.x, end = be.y;
  __syncthreads();

  float acc[16];
#pragma unroll
  for (int q = 0; q < 16; ++q) acc[q] = 0.f;

  if (fits) {
    const unsigned lb = span_beg;
    unsigned j = beg;
    for (; j + 8 <= end; j += 8) {
      int sn[8];
#pragma unroll
      for (int i = 0; i < 8; ++i) sn[i] = ssrc_l[j - lb + i];
      uint4 u[8];
#pragma unroll
      for (int i = 0; i < 8; ++i) u[i] = valb4[(size_t)sn[i] * P + p];
#pragma unroll
      for (int i = 0; i < 8; ++i) acc16(u[i], acc);
    }
    if (j < end) {
      const unsigned last = end - 1;
      int sn[8];
#pragma unroll
      for (int i = 0; i < 8; ++i) {
        unsigned jj = j + i;
        sn[i] = ssrc_l[(jj < last ? jj : last) - lb];
      }
      uint4 u[8];
#pragma unroll
      for (int i = 0; i < 8; ++i) u[i] = valb4[(size_t)sn[i] * P + p];
#pragma unroll
      for (int i = 0; i < 8; ++i) macc16(u[i], ((j + i) < end) ? 1.f : 0.f, acc);
    }
  } else {
    unsigned j = beg;
    for (; j + 8 <= end; j += 8) {
      int sn[8];
#pragma unroll
      for (int i = 0; i < 8; ++i) sn[i] = ssrc[j + i];
      uint4 u[8];
#pragma unroll
      for (int i = 0; i < 8; ++i) u[i] = valb4[(size_t)sn[i] * P + p];
#pragma unroll
      for (int i = 0; i < 8; ++i) acc16(u[i], acc);
    }
    if (j < end) {
      const unsigned last = end - 1;
      int sn[8];
#pragma unroll
      for (int i = 0; i < 8; ++i) {
        unsigned jj = j + i;
        sn[i] = ssrc[jj < last ? jj : last];
      }
      uint4 u[8];
#pragma unroll
      for (int i = 0; i < 8; ++i) u[i] = valb4[(size_t)sn[i] * P + p];
#pragma unroll
      for (int i = 0; i < 8; ++i) macc16(u[i], ((j + i) < end) ? 1.f : 0.f, acc);
    }
  }

  if (node < N) {
    const unsigned dg = end - beg;
    const float inv = dg ? 1.f / (float)dg : 0.f;
    const size_t o = (size_t)node * 32 + 16 * p;
#pragma unroll
    for (int q4 = 0; q4 < 4; ++q4) {
      float4 bv = *(const float4*)&base[o + 4 * q4];
      float4 ov;
      ov.x = acc[4 * q4 + 0] * inv + bv.x;
      ov.y = acc[4 * q4 + 1] * inv + bv.y;
      ov.z = acc[4 * q4 + 2] * inv + bv.z;
      ov.w = acc[4 * q4 + 3] * inv + bv.w;
      *(float4*)&out[o + 4 * q4] = ov;
    }
  }
}

extern "C" void kernel_launch(void* const* d_in, const int* in_sizes, int n_in,
                              void* d_out, int out_size, void* d_ws,
                              size_t ws_size, hipStream_t stream) {
  const float* x   = (const float*)d_in[0];
  const int*   ei  = (const int*)d_in[1];  // [2, E]: row0 = src, row1 = dst
  const float* W1n = (const float*)d_in[2];
  const float* W1s = (const float*)d_in[3];
  const float* b1  = (const float*)d_in[4];
  const float* W2n = (const float*)d_in[5];
  const float* W2s = (const float*)d_in[6];
  const float* b2  = (const float*)d_in[7];
  float* out = (float*)d_out;

  const int E = in_sizes[1] / 2;  // 1,600,000
  const int M = N_NODES;
  const int* src = ei;
  const int* dst = ei + E;
  const int NSB = (E + EPB - 1) / EPB;  // 196

  // Workspace layout (bytes):
  //   ep    @ 0           12,845,056  (NB*CAP u32; hnb8 aliases after bsort)
  //   ssrc  @ 12,845,056  12,845,056
  //   rows2 @ 25,690,112     802,816
  //   bcur  @ 26,492,928       3,136
  //   xnb8  @ 26,496,064   6,400,000  (fp8 M x 64)
  //   xsb   @ 32,896,064  12,800,000  (bf16 M x 64)
  //   hs    @ 45,696,064  12,800,000  (f32 M x 32)
  char* wsb = (char*)d_ws;
  unsigned*       ep    = (unsigned*)(wsb);
  int*            ssrc  = (int*)(wsb + 12845056);
  uint2*          rows2 = (uint2*)(wsb + 25690112);
  unsigned*       bcur  = (unsigned*)(wsb + 26492928);
  unsigned*       xnb8  = (unsigned*)(wsb + 26496064);
  unsigned short* xsb   = (unsigned short*)(wsb + 32896064);
  float*          hs    = (float*)(wsb + 45696064);
  unsigned*       hnb8  = (unsigned*)(wsb);  // aliases ep (dead after bsort)

  // 1) zero bucket cursors (3 KB)
  hipMemsetAsync(bcur, 0, NB * 4, stream);
  // 2) fusedA: 196-block edge scatter overlapped with layer-1 dual-GEMM
  fusedA_k<<<NSB + GB1, 256, 0, stream>>>(src, dst, bcur, ep, x, W1n, W1s, b1,
                                          xnb8, xsb, E, NSB, M);
  // 3) per-bucket counting sort -> ssrc runs + rows2
  bsort_k<<<NB, 256, 0, stream>>>(ep, bcur, ssrc, rows2);
  // 4) fused gather1 + gemm2 (LDS-staged ssrc span; W from L1)
  fgg_k<<<GB1, 256, 0, stream>>>((const uint4*)xnb8, ssrc, rows2, xsb, W2n,
                                 W2s, b2, hnb8, hs, M);
  // 5) out = mean(fp8(hn)[src]) + hs (LDS-staged ssrc span)
  gather2_k<<<(M + 127) / 128, 256, 0, stream>>>((const uint4*)hnb8, ssrc,
                                                 rows2, hs, out, M);
}

// Round 9
// 194.646 us; speedup vs baseline: 2.7915x; 1.0880x over previous
//
#include <hip/hip_runtime.h>
#include <hip/hip_bf16.h>

#define N_NODES 100000
#define NB 784   // buckets of 128 nodes: 784*128 = 100352 >= N_NODES
#define NPAD 100352
#define BSH 7
#define BMASK 127
#define CAP 4096  // static per-bucket capacity (mean 2040 -> safe)
#define MSTRIDE 36 // u32 stride of an LDS mean row (32 payload + 4 pad)
#define FNB 32     // nodes per fgg block (R22: 2-team split gather)

typedef float v2f __attribute__((ext_vector_type(2)));

__device__ inline void fma4(float a, const float4& w, float4& c) {
  c.x = fmaf(a, w.x, c.x);
  c.y = fmaf(a, w.y, c.y);
  c.z = fmaf(a, w.z, c.z);
  c.w = fmaf(a, w.w, c.w);
}
__device__ inline unsigned short f2bf(float f) {  // RNE f32->bf16
  unsigned u = __float_as_uint(f);
  u += 0x7fffu + ((u >> 16) & 1u);
  return (unsigned short)(u >> 16);
}
__device__ inline unsigned pack2bf(float a, float b) {
  return (unsigned)f2bf(a) | ((unsigned)f2bf(b) << 16);
}
__device__ inline unsigned packfp8x4(float a, float b, float c, float d) {
  int pk = __builtin_amdgcn_cvt_pk_fp8_f32(a, b, 0, false);
  pk = __builtin_amdgcn_cvt_pk_fp8_f32(c, d, pk, true);
  return (unsigned)pk;
}
// relu(bf16(m) + bf16(s)) for 4 packed bf16 elements (bit-identical f32 math)
__device__ inline float4 relu_mix(uint2 m, uint2 s) {
  float4 v;
  v.x = fmaxf(__uint_as_float(m.x << 16) + __uint_as_float(s.x << 16), 0.f);
  v.y = fmaxf(__uint_as_float(m.x & 0xffff0000u) +
                  __uint_as_float(s.x & 0xffff0000u), 0.f);
  v.z = fmaxf(__uint_as_float(m.y << 16) + __uint_as_float(s.y << 16), 0.f);
  v.w = fmaxf(__uint_as_float(m.y & 0xffff0000u) +
                  __uint_as_float(s.y & 0xffff0000u), 0.f);
  return v;
}
// accumulate 16 fp8-decoded floats from a uint4
__device__ inline void acc16(const uint4& u, float* acc) {
  v2f f0 = __builtin_amdgcn_cvt_pk_f32_fp8((int)u.x, false);
  v2f f1 = __builtin_amdgcn_cvt_pk_f32_fp8((int)u.x, true);
  v2f f2 = __builtin_amdgcn_cvt_pk_f32_fp8((int)u.y, false);
  v2f f3 = __builtin_amdgcn_cvt_pk_f32_fp8((int)u.y, true);
  v2f f4 = __builtin_amdgcn_cvt_pk_f32_fp8((int)u.z, false);
  v2f f5 = __builtin_amdgcn_cvt_pk_f32_fp8((int)u.z, true);
  v2f f6 = __builtin_amdgcn_cvt_pk_f32_fp8((int)u.w, false);
  v2f f7 = __builtin_amdgcn_cvt_pk_f32_fp8((int)u.w, true);
  acc[0] += f0[0];  acc[1] += f0[1];
  acc[2] += f1[0];  acc[3] += f1[1];
  acc[4] += f2[0];  acc[5] += f2[1];
  acc[6] += f3[0];  acc[7] += f3[1];
  acc[8] += f4[0];  acc[9] += f4[1];
  acc[10] += f5[0]; acc[11] += f5[1];
  acc[12] += f6[0]; acc[13] += f6[1];
  acc[14] += f7[0]; acc[15] += f7[1];
}
// masked accumulate (w in {0,1}; fmaf(1,f,a) == a+f bit-identically)
__device__ inline void macc16(const uint4& u, float w, float* acc) {
  v2f f0 = __builtin_amdgcn_cvt_pk_f32_fp8((int)u.x, false);
  v2f f1 = __builtin_amdgcn_cvt_pk_f32_fp8((int)u.x, true);
  v2f f2 = __builtin_amdgcn_cvt_pk_f32_fp8((int)u.y, false);
  v2f f3 = __builtin_amdgcn_cvt_pk_f32_fp8((int)u.y, true);
  v2f f4 = __builtin_amdgcn_cvt_pk_f32_fp8((int)u.z, false);
  v2f f5 = __builtin_amdgcn_cvt_pk_f32_fp8((int)u.z, true);
  v2f f6 = __builtin_amdgcn_cvt_pk_f32_fp8((int)u.w, false);
  v2f f7 = __builtin_amdgcn_cvt_pk_f32_fp8((int)u.w, true);
  acc[0] = fmaf(w, f0[0], acc[0]);   acc[1] = fmaf(w, f0[1], acc[1]);
  acc[2] = fmaf(w, f1[0], acc[2]);   acc[3] = fmaf(w, f1[1], acc[3]);
  acc[4] = fmaf(w, f2[0], acc[4]);   acc[5] = fmaf(w, f2[1], acc[5]);
  acc[6] = fmaf(w, f3[0], acc[6]);   acc[7] = fmaf(w, f3[1], acc[7]);
  acc[8] = fmaf(w, f4[0], acc[8]);   acc[9] = fmaf(w, f4[1], acc[9]);
  acc[10] = fmaf(w, f5[0], acc[10]); acc[11] = fmaf(w, f5[1], acc[11]);
  acc[12] = fmaf(w, f6[0], acc[12]); acc[13] = fmaf(w, f6[1], acc[13]);
  acc[14] = fmaf(w, f7[0], acc[14]); acc[15] = fmaf(w, f7[1], acc[15]);
}

#define EPB 8192   // edges per scatter block (R17 proven)
#define EPT 32     // edges per thread (256 threads)
#define GB1 1563   // ceil(100000/64)

// ---------------------------------------------------------------------------
// fusedA (FROZEN at R4 best): blocks [0,NSB) = scatter-only; blocks
// [NSB, NSB+GB1) = layer-1 dual-GEMM.
// ---------------------------------------------------------------------------
__global__ __launch_bounds__(256) void fusedA_k(
    const int* __restrict__ src, const int* __restrict__ dst,
    unsigned* __restrict__ bcur, unsigned* __restrict__ ep,
    const float* __restrict__ x, const float* __restrict__ W1n,
    const float* __restrict__ W1s, const float* __restrict__ b1,
    unsigned* __restrict__ xnb8, unsigned short* __restrict__ xsb,
    int E, int NSB, int M) {
  __shared__ __align__(16) float smem[8192];  // 32768 B
  const int tid = threadIdx.x;

  if ((int)blockIdx.x < NSB) {
    // ---------------- scatter body ----------------
    unsigned* lh = (unsigned*)smem;
    unsigned* lbase = lh + NB;
    for (int i = tid; i < NB; i += 256) lh[i] = 0;
    __syncthreads();
    const int ebase = blockIdx.x * EPB;
    unsigned rb[EPT];  // (rank<<10) | bucket
#pragma unroll
    for (int it = 0; it < EPT; ++it) {
      int e = ebase + it * 256 + tid;
      if (e < E) {
        unsigned b = ((unsigned)dst[e]) >> BSH;
        unsigned r = atomicAdd(&lh[b], 1u);  // r < 8192 -> fits in 22 bits
        rb[it] = (r << 10) | b;
      }
    }
    __syncthreads();
    for (int i = tid; i < NB; i += 256)
      lbase[i] = lh[i] ? atomicAdd(&bcur[i], lh[i]) : 0u;
    __syncthreads();
#pragma unroll
    for (int it = 0; it < EPT; ++it) {
      int e = ebase + it * 256 + tid;
      if (e < E) {
        unsigned b = rb[it] & 1023u;
        unsigned r = rb[it] >> 10;
        ep[(size_t)b * CAP + lbase[b] + r] =
            (((unsigned)src[e]) << BSH) | (((unsigned)dst[e]) & BMASK);
      }
    }
    return;
  }

  // ---------------- gemm1 body ----------------
  float* Wn = smem;
  float* Ws = smem + 4096;
  const int row0 = ((int)blockIdx.x - NSB) * 64;

  for (int i = tid; i < 1024; i += 256) {
    ((float4*)Wn)[i] = ((const float4*)W1n)[i];
    ((float4*)Ws)[i] = ((const float4*)W1s)[i];
  }

  const int tx = tid & 15;
  const int ty = tid >> 4;
  const int arow = ty * 4;

  const float* xr[4];
#pragma unroll
  for (int r = 0; r < 4; ++r) {
    long long gr = row0 + arow + r;
    if (gr >= M) gr = M - 1;
    xr[r] = x + gr * 64;
  }

  float4 an[4], as[4];
#pragma unroll
  for (int r = 0; r < 4; ++r) {
    an[r] = make_float4(0.f, 0.f, 0.f, 0.f);
    as[r] = make_float4(0.f, 0.f, 0.f, 0.f);
  }
  __syncthreads();

#pragma unroll 2
  for (int k4 = 0; k4 < 16; ++k4) {
    float4 a[4];
#pragma unroll
    for (int r = 0; r < 4; ++r) a[r] = *(const float4*)(xr[r] + 4 * k4);
    float4 wn0 = *(const float4*)&Wn[(4 * k4 + 0) * 64 + 4 * tx];
    float4 wn1 = *(const float4*)&Wn[(4 * k4 + 1) * 64 + 4 * tx];
    float4 wn2 = *(const float4*)&Wn[(4 * k4 + 2) * 64 + 4 * tx];
    float4 wn3 = *(const float4*)&Wn[(4 * k4 + 3) * 64 + 4 * tx];
    float4 ws0 = *(const float4*)&Ws[(4 * k4 + 0) * 64 + 4 * tx];
    float4 ws1 = *(const float4*)&Ws[(4 * k4 + 1) * 64 + 4 * tx];
    float4 ws2 = *(const float4*)&Ws[(4 * k4 + 2) * 64 + 4 * tx];
    float4 ws3 = *(const float4*)&Ws[(4 * k4 + 3) * 64 + 4 * tx];
#pragma unroll
    for (int r = 0; r < 4; ++r) {
      fma4(a[r].x, wn0, an[r]);
      fma4(a[r].y, wn1, an[r]);
      fma4(a[r].z, wn2, an[r]);
      fma4(a[r].w, wn3, an[r]);
      fma4(a[r].x, ws0, as[r]);
      fma4(a[r].y, ws1, as[r]);
      fma4(a[r].z, ws2, as[r]);
      fma4(a[r].w, ws3, as[r]);
    }
  }

  const float4 bv = *(const float4*)&b1[4 * tx];
#pragma unroll
  for (int r = 0; r < 4; ++r) {
    int row = row0 + arow + r;
    if (row < M) {
      ushort4 ps;
      ps.x = f2bf(as[r].x + bv.x);
      ps.y = f2bf(as[r].y + bv.y);
      ps.z = f2bf(as[r].z + bv.z);
      ps.w = f2bf(as[r].w + bv.w);
      *(ushort4*)&xsb[(long long)row * 64 + 4 * tx] = ps;
      xnb8[(size_t)row * 16 + tx] =
          packfp8x4(an[r].x, an[r].y, an[r].z, an[r].w);
    }
  }
}

// ---------------------------------------------------------------------------
// bsort (FROZEN): per-bucket counting sort -> per-node contiguous src runs.
// ---------------------------------------------------------------------------
__global__ __launch_bounds__(256) void bsort_k(const unsigned* __restrict__ ep,
                                               const unsigned* __restrict__ bcur,
                                               int* __restrict__ ssrc,
                                               uint2* __restrict__ rows2) {
  __shared__ unsigned cnt[128];
  __shared__ unsigned sc[128];
  const int tid = threadIdx.x;
  const int b = blockIdx.x;
  const unsigned cntb = bcur[b];
  const unsigned beg = (unsigned)(b * CAP);
  if (tid < 128) cnt[tid] = 0;
  __syncthreads();
  for (unsigned j = tid; j < cntb; j += 256)
    atomicAdd(&cnt[ep[(size_t)beg + j] & BMASK], 1u);
  __syncthreads();
  unsigned v = (tid < 128) ? cnt[tid] : 0u;
  if (tid < 128) sc[tid] = v;
  __syncthreads();
  for (int off = 1; off < 128; off <<= 1) {
    unsigned t = (tid < 128 && tid >= off) ? sc[tid - off] : 0u;
    __syncthreads();
    if (tid < 128) sc[tid] += t;
    __syncthreads();
  }
  if (tid < 128) {
    unsigned ex = sc[tid] - v;
    rows2[b * 128 + tid] = make_uint2(beg + ex, beg + ex + v);
    cnt[tid] = ex;
  }
  __syncthreads();
  for (unsigned j = tid; j < cntb; j += 256) {
    unsigned p = ep[(size_t)beg + j];
    unsigned r = atomicAdd(&cnt[p & BMASK], 1u);
    ssrc[(size_t)beg + r] = (int)(p >> BSH);
  }
}

// ---------------------------------------------------------------------------
// R22 fgg: fused gather1 + gemm2 per 32 nodes. vs R4: each node's edge list
// is SPLIT across 2 lane-teams (8 lanes/node = 2 teams x 4 col-quarters),
// halving the per-wave serial batch chain; partial sums combined with one
// __shfl_xor(.,4) per accumulator. Grid 1563 -> 3125. No added pre-work on
// the critical path (lesson of R20/R21 regressions). Gather math otherwise
// identical to R4 (clamped-dup tail + w-masked fmaf).
// ---------------------------------------------------------------------------
__global__ __launch_bounds__(256) void fgg_k(
    const uint4* __restrict__ valb4, const int* __restrict__ ssrc,
    const uint2* __restrict__ rows2, const unsigned short* __restrict__ xsb,
    const float* __restrict__ W2n, const float* __restrict__ W2s,
    const float* __restrict__ b2, unsigned* __restrict__ hnb8,
    float* __restrict__ hs, int M) {
  __shared__ float Wn[64 * 32];
  __shared__ float Ws[64 * 32];
  __shared__ unsigned mlds[FNB * MSTRIDE];  // 4608 B
  const int tid = threadIdx.x;
  const int node0 = blockIdx.x * FNB;  // 3125*32 = 100000 exactly

  for (int i = tid; i < 512; i += 256) {
    ((float4*)Wn)[i] = ((const float4*)W2n)[i];
    ((float4*)Ws)[i] = ((const float4*)W2s)[i];
  }

  // ---- gather phase: 8 lanes/node = 2 teams x 4 col-quarters ----
  const int lrow = tid >> 3;           // 0..31
  const int q = tid & 7;
  const int p = q & 3;                 // column quarter (16 fp8 each)
  const int t = q >> 2;                // team
  const int node = node0 + lrow;       // < 100000 always
  const uint2 be = rows2[node];
  const unsigned dg = be.y - be.x;
  const unsigned mid = be.x + ((dg + 1) >> 1);
  const unsigned tb = t ? mid : be.x;
  const unsigned te = t ? be.y : mid;

  float acc[16];
#pragma unroll
  for (int qq = 0; qq < 16; ++qq) acc[qq] = 0.f;

  unsigned j = tb;
  for (; j + 8 <= te; j += 8) {
    int sn[8];
#pragma unroll
    for (int i = 0; i < 8; ++i) sn[i] = ssrc[j + i];
    uint4 u[8];
#pragma unroll
    for (int i = 0; i < 8; ++i) u[i] = valb4[(size_t)sn[i] * 4 + p];
#pragma unroll
    for (int i = 0; i < 8; ++i) acc16(u[i], acc);
  }
  if (j < te) {
    const unsigned last = te - 1;
    int sn[8];
#pragma unroll
    for (int i = 0; i < 8; ++i) {
      unsigned jj = j + i;
      sn[i] = ssrc[jj < last ? jj : last];
    }
    uint4 u[8];
#pragma unroll
    for (int i = 0; i < 8; ++i) u[i] = valb4[(size_t)sn[i] * 4 + p];
#pragma unroll
    for (int i = 0; i < 8; ++i) macc16(u[i], ((j + i) < te) ? 1.f : 0.f, acc);
  }

  // combine teams (partner lane = tid^4, same wave)
#pragma unroll
  for (int qq = 0; qq < 16; ++qq) acc[qq] += __shfl_xor(acc[qq], 4);

  const float inv = dg ? 1.f / (float)dg : 0.f;
  if (t == 0) {
    uint4 pk;
    pk.x = pack2bf(acc[0] * inv, acc[1] * inv);
    pk.y = pack2bf(acc[2] * inv, acc[3] * inv);
    pk.z = pack2bf(acc[4] * inv, acc[5] * inv);
    pk.w = pack2bf(acc[6] * inv, acc[7] * inv);
    *(uint4*)&mlds[lrow * MSTRIDE + p * 8] = pk;
  } else {
    uint4 pk;
    pk.x = pack2bf(acc[8] * inv, acc[9] * inv);
    pk.y = pack2bf(acc[10] * inv, acc[11] * inv);
    pk.z = pack2bf(acc[12] * inv, acc[13] * inv);
    pk.w = pack2bf(acc[14] * inv, acc[15] * inv);
    *(uint4*)&mlds[lrow * MSTRIDE + p * 8 + 4] = pk;
  }
  __syncthreads();

  // ---- GEMM phase: 32 rows x dual 32 cols, 1 row/thread ----
  const int tx = tid & 7;
  const int ty = tid >> 3;  // 0..31 -> row
  const uint2* mp = (const uint2*)&mlds[ty * MSTRIDE];
  const uint2* sp = (const uint2*)(xsb + (long long)(node0 + ty) * 64);

  float4 an = make_float4(0.f, 0.f, 0.f, 0.f);
  float4 asv = make_float4(0.f, 0.f, 0.f, 0.f);

#pragma unroll 2
  for (int k4 = 0; k4 < 16; ++k4) {
    float4 a = relu_mix(mp[k4], sp[k4]);
    float4 wn0 = *(const float4*)&Wn[(4 * k4 + 0) * 32 + 4 * tx];
    float4 wn1 = *(const float4*)&Wn[(4 * k4 + 1) * 32 + 4 * tx];
    float4 wn2 = *(const float4*)&Wn[(4 * k4 + 2) * 32 + 4 * tx];
    float4 wn3 = *(const float4*)&Wn[(4 * k4 + 3) * 32 + 4 * tx];
    float4 ws0 = *(const float4*)&Ws[(4 * k4 + 0) * 32 + 4 * tx];
    float4 ws1 = *(const float4*)&Ws[(4 * k4 + 1) * 32 + 4 * tx];
    float4 ws2 = *(const float4*)&Ws[(4 * k4 + 2) * 32 + 4 * tx];
    float4 ws3 = *(const float4*)&Ws[(4 * k4 + 3) * 32 + 4 * tx];
    fma4(a.x, wn0, an);
    fma4(a.y, wn1, an);
    fma4(a.z, wn2, an);
    fma4(a.w, wn3, an);
    fma4(a.x, ws0, asv);
    fma4(a.y, ws1, asv);
    fma4(a.z, ws2, asv);
    fma4(a.w, ws3, asv);
  }

  const float4 bv = *(const float4*)&b2[4 * tx];
  const int row = node0 + ty;  // < 100000 always
  float4 o;
  o.x = asv.x + bv.x;
  o.y = asv.y + bv.y;
  o.z = asv.z + bv.z;
  o.w = asv.w + bv.w;
  *(float4*)&hs[(long long)row * 32 + 4 * tx] = o;
  hnb8[(size_t)row * 8 + tx] = packfp8x4(an.x, an.y, an.z, an.w);
}

// ---------------------------------------------------------------------------
// R22 gather2: out[node] = mean_j fp8decode(hnb8[ssrc[j]]) + hs[node].
// 64 nodes/block (4 lanes/node = 2 teams x 2 col-halves); grid 782 -> 1563
// (waves/CU 12 -> 24) and per-wave serial batches halved. Combine via
// __shfl_xor(.,2); each team-lane writes its half of the 16 outputs.
// ---------------------------------------------------------------------------
__global__ __launch_bounds__(256) void gather2_k(
    const uint4* __restrict__ valb4, const int* __restrict__ ssrc,
    const uint2* __restrict__ rows2, const float* __restrict__ base,
    float* __restrict__ out, int N) {
  const int tid = threadIdx.x;
  const int node0 = blockIdx.x * 64;
  const int lrow = tid >> 2;           // 0..63
  const int q = tid & 3;
  const int p = q & 1;                 // column half (16 fp8 each)
  const int t = q >> 1;                // team
  const int node = node0 + lrow;       // < 100032 <= NPAD: rows2 valid
  const uint2 be = rows2[node];
  const unsigned dg = be.y - be.x;
  const unsigned mid = be.x + ((dg + 1) >> 1);
  const unsigned tb = t ? mid : be.x;
  const unsigned te = t ? be.y : mid;

  float acc[16];
#pragma unroll
  for (int qq = 0; qq < 16; ++qq) acc[qq] = 0.f;

  unsigned j = tb;
  for (; j + 8 <= te; j += 8) {
    int sn[8];
#pragma unroll
    for (int i = 0; i < 8; ++i) sn[i] = ssrc[j + i];
    uint4 u[8];
#pragma unroll
    for (int i = 0; i < 8; ++i) u[i] = valb4[(size_t)sn[i] * 2 + p];
#pragma unroll
    for (int i = 0; i < 8; ++i) acc16(u[i], acc);
  }
  if (j < te) {
    const unsigned last = te - 1;
    int sn[8];
#pragma unroll
    for (int i = 0; i < 8; ++i) {
      unsigned jj = j + i;
      sn[i] = ssrc[jj < last ? jj : last];
    }
    uint4 u[8];
#pragma unroll
    for (int i = 0; i < 8; ++i) u[i] = valb4[(size_t)sn[i] * 2 + p];
#pragma unroll
    for (int i = 0; i < 8; ++i) macc16(u[i], ((j + i) < te) ? 1.f : 0.f, acc);
  }

  // combine teams (partner lane = tid^2, same wave)
#pragma unroll
  for (int qq = 0; qq < 16; ++qq) acc[qq] += __shfl_xor(acc[qq], 2);

  if (node < N) {
    const float inv = dg ? 1.f / (float)dg : 0.f;
    const size_t o = (size_t)node * 32 + 16 * p;
#pragma unroll
    for (int h = 0; h < 2; ++h) {
      const int q4 = 2 * t + h;
      float4 bv = *(const float4*)&base[o + 4 * q4];
      float4 ov;
      ov.x = acc[4 * q4 + 0] * inv + bv.x;
      ov.y = acc[4 * q4 + 1] * inv + bv.y;
      ov.z = acc[4 * q4 + 2] * inv + bv.z;
      ov.w = acc[4 * q4 + 3] * inv + bv.w;
      *(float4*)&out[o + 4 * q4] = ov;
    }
  }
}

extern "C" void kernel_launch(void* const* d_in, const int* in_sizes, int n_in,
                              void* d_out, int out_size, void* d_ws,
                              size_t ws_size, hipStream_t stream) {
  const float* x   = (const float*)d_in[0];
  const int*   ei  = (const int*)d_in[1];  // [2, E]: row0 = src, row1 = dst
  const float* W1n = (const float*)d_in[2];
  const float* W1s = (const float*)d_in[3];
  const float* b1  = (const float*)d_in[4];
  const float* W2n = (const float*)d_in[5];
  const float* W2s = (const float*)d_in[6];
  const float* b2  = (const float*)d_in[7];
  float* out = (float*)d_out;

  const int E = in_sizes[1] / 2;  // 1,600,000
  const int M = N_NODES;
  const int* src = ei;
  const int* dst = ei + E;
  const int NSB = (E + EPB - 1) / EPB;  // 196

  // Workspace layout (bytes):
  //   ep    @ 0           12,845,056  (NB*CAP u32; hnb8 aliases after bsort)
  //   ssrc  @ 12,845,056  12,845,056
  //   rows2 @ 25,690,112     802,816
  //   bcur  @ 26,492,928       3,136
  //   xnb8  @ 26,496,064   6,400,000  (fp8 M x 64)
  //   xsb   @ 32,896,064  12,800,000  (bf16 M x 64)
  //   hs    @ 45,696,064  12,800,000  (f32 M x 32)
  char* wsb = (char*)d_ws;
  unsigned*       ep    = (unsigned*)(wsb);
  int*            ssrc  = (int*)(wsb + 12845056);
  uint2*          rows2 = (uint2*)(wsb + 25690112);
  unsigned*       bcur  = (unsigned*)(wsb + 26492928);
  unsigned*       xnb8  = (unsigned*)(wsb + 26496064);
  unsigned short* xsb   = (unsigned short*)(wsb + 32896064);
  float*          hs    = (float*)(wsb + 45696064);
  unsigned*       hnb8  = (unsigned*)(wsb);  // aliases ep (dead after bsort)

  // 1) zero bucket cursors (3 KB)
  hipMemsetAsync(bcur, 0, NB * 4, stream);
  // 2) fusedA: 196-block edge scatter overlapped with layer-1 dual-GEMM
  fusedA_k<<<NSB + GB1, 256, 0, stream>>>(src, dst, bcur, ep, x, W1n, W1s, b1,
                                          xnb8, xsb, E, NSB, M);
  // 3) per-bucket counting sort -> ssrc runs + rows2
  bsort_k<<<NB, 256, 0, stream>>>(ep, bcur, ssrc, rows2);
  // 4) fused gather1 + gemm2 (2-team split gather; 32 nodes/block)
  fgg_k<<<(M + FNB - 1) / FNB, 256, 0, stream>>>((const uint4*)xnb8, ssrc,
                                                 rows2, xsb, W2n, W2s, b2,
                                                 hnb8, hs, M);
  // 5) out = mean(fp8(hn)[src]) + hs (2-team split gather; 64 nodes/block)
  gather2_k<<<(M + 63) / 64, 256, 0, stream>>>((const uint4*)hnb8, ssrc,
                                               rows2, hs, out, M);
}

// Round 10
// 193.592 us; speedup vs baseline: 2.8067x; 1.0054x over previous
//
#include <hip/hip_runtime.h>
#include <hip/hip_bf16.h>

#define N_NODES 100000
#define NB 784   // buckets of 128 nodes: 784*128 = 100352 >= N_NODES
#define NPAD 100352
#define BSH 7
#define BMASK 127
#define CAP 4096  // static per-bucket capacity (mean 2040 -> safe)
#define MSTRIDE 36 // u32 stride of an LDS mean row (32 payload + 4 pad)
#define FNB 32     // nodes per fgg block (R22: 2-team split gather)

typedef float v2f __attribute__((ext_vector_type(2)));

__device__ inline void fma4(float a, const float4& w, float4& c) {
  c.x = fmaf(a, w.x, c.x);
  c.y = fmaf(a, w.y, c.y);
  c.z = fmaf(a, w.z, c.z);
  c.w = fmaf(a, w.w, c.w);
}
__device__ inline unsigned short f2bf(float f) {  // RNE f32->bf16
  unsigned u = __float_as_uint(f);
  u += 0x7fffu + ((u >> 16) & 1u);
  return (unsigned short)(u >> 16);
}
__device__ inline unsigned pack2bf(float a, float b) {
  return (unsigned)f2bf(a) | ((unsigned)f2bf(b) << 16);
}
__device__ inline unsigned packfp8x4(float a, float b, float c, float d) {
  int pk = __builtin_amdgcn_cvt_pk_fp8_f32(a, b, 0, false);
  pk = __builtin_amdgcn_cvt_pk_fp8_f32(c, d, pk, true);
  return (unsigned)pk;
}
// relu(bf16(m) + bf16(s)) for 4 packed bf16 elements (bit-identical f32 math)
__device__ inline float4 relu_mix(uint2 m, uint2 s) {
  float4 v;
  v.x = fmaxf(__uint_as_float(m.x << 16) + __uint_as_float(s.x << 16), 0.f);
  v.y = fmaxf(__uint_as_float(m.x & 0xffff0000u) +
                  __uint_as_float(s.x & 0xffff0000u), 0.f);
  v.z = fmaxf(__uint_as_float(m.y << 16) + __uint_as_float(s.y << 16), 0.f);
  v.w = fmaxf(__uint_as_float(m.y & 0xffff0000u) +
                  __uint_as_float(s.y & 0xffff0000u), 0.f);
  return v;
}
// accumulate 16 fp8-decoded floats from a uint4
__device__ inline void acc16(const uint4& u, float* acc) {
  v2f f0 = __builtin_amdgcn_cvt_pk_f32_fp8((int)u.x, false);
  v2f f1 = __builtin_amdgcn_cvt_pk_f32_fp8((int)u.x, true);
  v2f f2 = __builtin_amdgcn_cvt_pk_f32_fp8((int)u.y, false);
  v2f f3 = __builtin_amdgcn_cvt_pk_f32_fp8((int)u.y, true);
  v2f f4 = __builtin_amdgcn_cvt_pk_f32_fp8((int)u.z, false);
  v2f f5 = __builtin_amdgcn_cvt_pk_f32_fp8((int)u.z, true);
  v2f f6 = __builtin_amdgcn_cvt_pk_f32_fp8((int)u.w, false);
  v2f f7 = __builtin_amdgcn_cvt_pk_f32_fp8((int)u.w, true);
  acc[0] += f0[0];  acc[1] += f0[1];
  acc[2] += f1[0];  acc[3] += f1[1];
  acc[4] += f2[0];  acc[5] += f2[1];
  acc[6] += f3[0];  acc[7] += f3[1];
  acc[8] += f4[0];  acc[9] += f4[1];
  acc[10] += f5[0]; acc[11] += f5[1];
  acc[12] += f6[0]; acc[13] += f6[1];
  acc[14] += f7[0]; acc[15] += f7[1];
}
// masked accumulate (w in {0,1}; fmaf(1,f,a) == a+f bit-identically)
__device__ inline void macc16(const uint4& u, float w, float* acc) {
  v2f f0 = __builtin_amdgcn_cvt_pk_f32_fp8((int)u.x, false);
  v2f f1 = __builtin_amdgcn_cvt_pk_f32_fp8((int)u.x, true);
  v2f f2 = __builtin_amdgcn_cvt_pk_f32_fp8((int)u.y, false);
  v2f f3 = __builtin_amdgcn_cvt_pk_f32_fp8((int)u.y, true);
  v2f f4 = __builtin_amdgcn_cvt_pk_f32_fp8((int)u.z, false);
  v2f f5 = __builtin_amdgcn_cvt_pk_f32_fp8((int)u.z, true);
  v2f f6 = __builtin_amdgcn_cvt_pk_f32_fp8((int)u.w, false);
  v2f f7 = __builtin_amdgcn_cvt_pk_f32_fp8((int)u.w, true);
  acc[0] = fmaf(w, f0[0], acc[0]);   acc[1] = fmaf(w, f0[1], acc[1]);
  acc[2] = fmaf(w, f1[0], acc[2]);   acc[3] = fmaf(w, f1[1], acc[3]);
  acc[4] = fmaf(w, f2[0], acc[4]);   acc[5] = fmaf(w, f2[1], acc[5]);
  acc[6] = fmaf(w, f3[0], acc[6]);   acc[7] = fmaf(w, f3[1], acc[7]);
  acc[8] = fmaf(w, f4[0], acc[8]);   acc[9] = fmaf(w, f4[1], acc[9]);
  acc[10] = fmaf(w, f5[0], acc[10]); acc[11] = fmaf(w, f5[1], acc[11]);
  acc[12] = fmaf(w, f6[0], acc[12]); acc[13] = fmaf(w, f6[1], acc[13]);
  acc[14] = fmaf(w, f7[0], acc[14]); acc[15] = fmaf(w, f7[1], acc[15]);
}

#define EPB 8192   // edges per scatter block (196 blocks: amplification knob)
#define EPT 16     // edges per thread (512 threads; R23: 8-wave TLP)
#define GB2 782    // ceil(100000/128) gemm1 tiles (128 rows, 512 thr)

// ---------------------------------------------------------------------------
// R23 fusedA: 512-thread blocks. Scatter blocks keep EPB=8192 (196 blocks —
// same write-amplification as R4 best) but run 8 waves instead of 4: 2x TLP
// to hide the load->LDS-atomic->store chain that left R4's scatter at 57us
// with ~12us of actual issue work. gemm1 tiles are 128 rows (2x R4's 64,
// same per-thread work/registers).
// ---------------------------------------------------------------------------
__global__ __launch_bounds__(512) void fusedA_k(
    const int* __restrict__ src, const int* __restrict__ dst,
    unsigned* __restrict__ bcur, unsigned* __restrict__ ep,
    const float* __restrict__ x, const float* __restrict__ W1n,
    const float* __restrict__ W1s, const float* __restrict__ b1,
    unsigned* __restrict__ xnb8, unsigned short* __restrict__ xsb,
    int E, int NSB, int M) {
  __shared__ __align__(16) float smem[8192];  // 32768 B
  const int tid = threadIdx.x;

  if ((int)blockIdx.x < NSB) {
    // ---------------- scatter body (8 waves) ----------------
    unsigned* lh = (unsigned*)smem;
    unsigned* lbase = lh + NB;
    for (int i = tid; i < NB; i += 512) lh[i] = 0;
    __syncthreads();
    const int ebase = blockIdx.x * EPB;
    unsigned rb[EPT];  // (rank<<10) | bucket
#pragma unroll
    for (int it = 0; it < EPT; ++it) {
      int e = ebase + it * 512 + tid;
      if (e < E) {
        unsigned b = ((unsigned)dst[e]) >> BSH;
        unsigned r = atomicAdd(&lh[b], 1u);  // r < 8192 -> fits in 22 bits
        rb[it] = (r << 10) | b;
      }
    }
    __syncthreads();
    for (int i = tid; i < NB; i += 512)
      lbase[i] = lh[i] ? atomicAdd(&bcur[i], lh[i]) : 0u;
    __syncthreads();
#pragma unroll
    for (int it = 0; it < EPT; ++it) {
      int e = ebase + it * 512 + tid;
      if (e < E) {
        unsigned b = rb[it] & 1023u;
        unsigned r = rb[it] >> 10;
        ep[(size_t)b * CAP + lbase[b] + r] =
            (((unsigned)src[e]) << BSH) | (((unsigned)dst[e]) & BMASK);
      }
    }
    return;
  }

  // ---------------- gemm1 body: 128-row tile, 512 threads ----------------
  float* Wn = smem;
  float* Ws = smem + 4096;
  const int row0 = ((int)blockIdx.x - NSB) * 128;

  for (int i = tid; i < 1024; i += 512) {
    ((float4*)Wn)[i] = ((const float4*)W1n)[i];
    ((float4*)Ws)[i] = ((const float4*)W1s)[i];
  }

  const int tx = tid & 15;
  const int ty = tid >> 4;   // 0..31
  const int arow = ty * 4;   // 0..124

  const float* xr[4];
#pragma unroll
  for (int r = 0; r < 4; ++r) {
    long long gr = row0 + arow + r;
    if (gr >= M) gr = M - 1;
    xr[r] = x + gr * 64;
  }

  float4 an[4], as[4];
#pragma unroll
  for (int r = 0; r < 4; ++r) {
    an[r] = make_float4(0.f, 0.f, 0.f, 0.f);
    as[r] = make_float4(0.f, 0.f, 0.f, 0.f);
  }
  __syncthreads();

#pragma unroll 2
  for (int k4 = 0; k4 < 16; ++k4) {
    float4 a[4];
#pragma unroll
    for (int r = 0; r < 4; ++r) a[r] = *(const float4*)(xr[r] + 4 * k4);
    float4 wn0 = *(const float4*)&Wn[(4 * k4 + 0) * 64 + 4 * tx];
    float4 wn1 = *(const float4*)&Wn[(4 * k4 + 1) * 64 + 4 * tx];
    float4 wn2 = *(const float4*)&Wn[(4 * k4 + 2) * 64 + 4 * tx];
    float4 wn3 = *(const float4*)&Wn[(4 * k4 + 3) * 64 + 4 * tx];
    float4 ws0 = *(const float4*)&Ws[(4 * k4 + 0) * 64 + 4 * tx];
    float4 ws1 = *(const float4*)&Ws[(4 * k4 + 1) * 64 + 4 * tx];
    float4 ws2 = *(const float4*)&Ws[(4 * k4 + 2) * 64 + 4 * tx];
    float4 ws3 = *(const float4*)&Ws[(4 * k4 + 3) * 64 + 4 * tx];
#pragma unroll
    for (int r = 0; r < 4; ++r) {
      fma4(a[r].x, wn0, an[r]);
      fma4(a[r].y, wn1, an[r]);
      fma4(a[r].z, wn2, an[r]);
      fma4(a[r].w, wn3, an[r]);
      fma4(a[r].x, ws0, as[r]);
      fma4(a[r].y, ws1, as[r]);
      fma4(a[r].z, ws2, as[r]);
      fma4(a[r].w, ws3, as[r]);
    }
  }

  const float4 bv = *(const float4*)&b1[4 * tx];
#pragma unroll
  for (int r = 0; r < 4; ++r) {
    int row = row0 + arow + r;
    if (row < M) {
      ushort4 ps;
      ps.x = f2bf(as[r].x + bv.x);
      ps.y = f2bf(as[r].y + bv.y);
      ps.z = f2bf(as[r].z + bv.z);
      ps.w = f2bf(as[r].w + bv.w);
      *(ushort4*)&xsb[(long long)row * 64 + 4 * tx] = ps;
      xnb8[(size_t)row * 16 + tx] =
          packfp8x4(an[r].x, an[r].y, an[r].z, an[r].w);
    }
  }
}

// ---------------------------------------------------------------------------
// bsort (FROZEN): per-bucket counting sort -> per-node contiguous src runs.
// ---------------------------------------------------------------------------
__global__ __launch_bounds__(256) void bsort_k(const unsigned* __restrict__ ep,
                                               const unsigned* __restrict__ bcur,
                                               int* __restrict__ ssrc,
                                               uint2* __restrict__ rows2) {
  __shared__ unsigned cnt[128];
  __shared__ unsigned sc[128];
  const int tid = threadIdx.x;
  const int b = blockIdx.x;
  const unsigned cntb = bcur[b];
  const unsigned beg = (unsigned)(b * CAP);
  if (tid < 128) cnt[tid] = 0;
  __syncthreads();
  for (unsigned j = tid; j < cntb; j += 256)
    atomicAdd(&cnt[ep[(size_t)beg + j] & BMASK], 1u);
  __syncthreads();
  unsigned v = (tid < 128) ? cnt[tid] : 0u;
  if (tid < 128) sc[tid] = v;
  __syncthreads();
  for (int off = 1; off < 128; off <<= 1) {
    unsigned t = (tid < 128 && tid >= off) ? sc[tid - off] : 0u;
    __syncthreads();
    if (tid < 128) sc[tid] += t;
    __syncthreads();
  }
  if (tid < 128) {
    unsigned ex = sc[tid] - v;
    rows2[b * 128 + tid] = make_uint2(beg + ex, beg + ex + v);
    cnt[tid] = ex;
  }
  __syncthreads();
  for (unsigned j = tid; j < cntb; j += 256) {
    unsigned p = ep[(size_t)beg + j];
    unsigned r = atomicAdd(&cnt[p & BMASK], 1u);
    ssrc[(size_t)beg + r] = (int)(p >> BSH);
  }
}

// ---------------------------------------------------------------------------
// fgg (FROZEN at R9 best): fused gather1 + gemm2 per 32 nodes; 2-team split
// gather (8 lanes/node), __shfl_xor(.,4) combine.
// ---------------------------------------------------------------------------
__global__ __launch_bounds__(256) void fgg_k(
    const uint4* __restrict__ valb4, const int* __restrict__ ssrc,
    const uint2* __restrict__ rows2, const unsigned short* __restrict__ xsb,
    const float* __restrict__ W2n, const float* __restrict__ W2s,
    const float* __restrict__ b2, unsigned* __restrict__ hnb8,
    float* __restrict__ hs, int M) {
  __shared__ float Wn[64 * 32];
  __shared__ float Ws[64 * 32];
  __shared__ unsigned mlds[FNB * MSTRIDE];  // 4608 B
  const int tid = threadIdx.x;
  const int node0 = blockIdx.x * FNB;  // 3125*32 = 100000 exactly

  for (int i = tid; i < 512; i += 256) {
    ((float4*)Wn)[i] = ((const float4*)W2n)[i];
    ((float4*)Ws)[i] = ((const float4*)W2s)[i];
  }

  // ---- gather phase: 8 lanes/node = 2 teams x 4 col-quarters ----
  const int lrow = tid >> 3;           // 0..31
  const int q = tid & 7;
  const int p = q & 3;                 // column quarter (16 fp8 each)
  const int t = q >> 2;                // team
  const int node = node0 + lrow;       // < 100000 always
  const uint2 be = rows2[node];
  const unsigned dg = be.y - be.x;
  const unsigned mid = be.x + ((dg + 1) >> 1);
  const unsigned tb = t ? mid : be.x;
  const unsigned te = t ? be.y : mid;

  float acc[16];
#pragma unroll
  for (int qq = 0; qq < 16; ++qq) acc[qq] = 0.f;

  unsigned j = tb;
  for (; j + 8 <= te; j += 8) {
    int sn[8];
#pragma unroll
    for (int i = 0; i < 8; ++i) sn[i] = ssrc[j + i];
    uint4 u[8];
#pragma unroll
    for (int i = 0; i < 8; ++i) u[i] = valb4[(size_t)sn[i] * 4 + p];
#pragma unroll
    for (int i = 0; i < 8; ++i) acc16(u[i], acc);
  }
  if (j < te) {
    const unsigned last = te - 1;
    int sn[8];
#pragma unroll
    for (int i = 0; i < 8; ++i) {
      unsigned jj = j + i;
      sn[i] = ssrc[jj < last ? jj : last];
    }
    uint4 u[8];
#pragma unroll
    for (int i = 0; i < 8; ++i) u[i] = valb4[(size_t)sn[i] * 4 + p];
#pragma unroll
    for (int i = 0; i < 8; ++i) macc16(u[i], ((j + i) < te) ? 1.f : 0.f, acc);
  }

  // combine teams (partner lane = tid^4, same wave)
#pragma unroll
  for (int qq = 0; qq < 16; ++qq) acc[qq] += __shfl_xor(acc[qq], 4);

  const float inv = dg ? 1.f / (float)dg : 0.f;
  if (t == 0) {
    uint4 pk;
    pk.x = pack2bf(acc[0] * inv, acc[1] * inv);
    pk.y = pack2bf(acc[2] * inv, acc[3] * inv);
    pk.z = pack2bf(acc[4] * inv, acc[5] * inv);
    pk.w = pack2bf(acc[6] * inv, acc[7] * inv);
    *(uint4*)&mlds[lrow * MSTRIDE + p * 8] = pk;
  } else {
    uint4 pk;
    pk.x = pack2bf(acc[8] * inv, acc[9] * inv);
    pk.y = pack2bf(acc[10] * inv, acc[11] * inv);
    pk.z = pack2bf(acc[12] * inv, acc[13] * inv);
    pk.w = pack2bf(acc[14] * inv, acc[15] * inv);
    *(uint4*)&mlds[lrow * MSTRIDE + p * 8 + 4] = pk;
  }
  __syncthreads();

  // ---- GEMM phase: 32 rows x dual 32 cols, 1 row/thread ----
  const int tx = tid & 7;
  const int ty = tid >> 3;  // 0..31 -> row
  const uint2* mp = (const uint2*)&mlds[ty * MSTRIDE];
  const uint2* sp = (const uint2*)(xsb + (long long)(node0 + ty) * 64);

  float4 an = make_float4(0.f, 0.f, 0.f, 0.f);
  float4 asv = make_float4(0.f, 0.f, 0.f, 0.f);

#pragma unroll 2
  for (int k4 = 0; k4 < 16; ++k4) {
    float4 a = relu_mix(mp[k4], sp[k4]);
    float4 wn0 = *(const float4*)&Wn[(4 * k4 + 0) * 32 + 4 * tx];
    float4 wn1 = *(const float4*)&Wn[(4 * k4 + 1) * 32 + 4 * tx];
    float4 wn2 = *(const float4*)&Wn[(4 * k4 + 2) * 32 + 4 * tx];
    float4 wn3 = *(const float4*)&Wn[(4 * k4 + 3) * 32 + 4 * tx];
    float4 ws0 = *(const float4*)&Ws[(4 * k4 + 0) * 32 + 4 * tx];
    float4 ws1 = *(const float4*)&Ws[(4 * k4 + 1) * 32 + 4 * tx];
    float4 ws2 = *(const float4*)&Ws[(4 * k4 + 2) * 32 + 4 * tx];
    float4 ws3 = *(const float4*)&Ws[(4 * k4 + 3) * 32 + 4 * tx];
    fma4(a.x, wn0, an);
    fma4(a.y, wn1, an);
    fma4(a.z, wn2, an);
    fma4(a.w, wn3, an);
    fma4(a.x, ws0, asv);
    fma4(a.y, ws1, asv);
    fma4(a.z, ws2, asv);
    fma4(a.w, ws3, asv);
  }

  const float4 bv = *(const float4*)&b2[4 * tx];
  const int row = node0 + ty;  // < 100000 always
  float4 o;
  o.x = asv.x + bv.x;
  o.y = asv.y + bv.y;
  o.z = asv.z + bv.z;
  o.w = asv.w + bv.w;
  *(float4*)&hs[(long long)row * 32 + 4 * tx] = o;
  hnb8[(size_t)row * 8 + tx] = packfp8x4(an.x, an.y, an.z, an.w);
}

// ---------------------------------------------------------------------------
// gather2 (FROZEN at R9 best): 64 nodes/block, 2-team split gather,
// __shfl_xor(.,2) combine; each team-lane writes its half of the outputs.
// ---------------------------------------------------------------------------
__global__ __launch_bounds__(256) void gather2_k(
    const uint4* __restrict__ valb4, const int* __restrict__ ssrc,
    const uint2* __restrict__ rows2, const float* __restrict__ base,
    float* __restrict__ out, int N) {
  const int tid = threadIdx.x;
  const int node0 = blockIdx.x * 64;
  const int lrow = tid >> 2;           // 0..63
  const int q = tid & 3;
  const int p = q & 1;                 // column half (16 fp8 each)
  const int t = q >> 1;                // team
  const int node = node0 + lrow;       // < 100032 <= NPAD: rows2 valid
  const uint2 be = rows2[node];
  const unsigned dg = be.y - be.x;
  const unsigned mid = be.x + ((dg + 1) >> 1);
  const unsigned tb = t ? mid : be.x;
  const unsigned te = t ? be.y : mid;

  float acc[16];
#pragma unroll
  for (int qq = 0; qq < 16; ++qq) acc[qq] = 0.f;

  unsigned j = tb;
  for (; j + 8 <= te; j += 8) {
    int sn[8];
#pragma unroll
    for (int i = 0; i < 8; ++i) sn[i] = ssrc[j + i];
    uint4 u[8];
#pragma unroll
    for (int i = 0; i < 8; ++i) u[i] = valb4[(size_t)sn[i] * 2 + p];
#pragma unroll
    for (int i = 0; i < 8; ++i) acc16(u[i], acc);
  }
  if (j < te) {
    const unsigned last = te - 1;
    int sn[8];
#pragma unroll
    for (int i = 0; i < 8; ++i) {
      unsigned jj = j + i;
      sn[i] = ssrc[jj < last ? jj : last];
    }
    uint4 u[8];
#pragma unroll
    for (int i = 0; i < 8; ++i) u[i] = valb4[(size_t)sn[i] * 2 + p];
#pragma unroll
    for (int i = 0; i < 8; ++i) macc16(u[i], ((j + i) < te) ? 1.f : 0.f, acc);
  }

  // combine teams (partner lane = tid^2, same wave)
#pragma unroll
  for (int qq = 0; qq < 16; ++qq) acc[qq] += __shfl_xor(acc[qq], 2);

  if (node < N) {
    const float inv = dg ? 1.f / (float)dg : 0.f;
    const size_t o = (size_t)node * 32 + 16 * p;
#pragma unroll
    for (int h = 0; h < 2; ++h) {
      const int q4 = 2 * t + h;
      float4 bv = *(const float4*)&base[o + 4 * q4];
      float4 ov;
      ov.x = acc[4 * q4 + 0] * inv + bv.x;
      ov.y = acc[4 * q4 + 1] * inv + bv.y;
      ov.z = acc[4 * q4 + 2] * inv + bv.z;
      ov.w = acc[4 * q4 + 3] * inv + bv.w;
      *(float4*)&out[o + 4 * q4] = ov;
    }
  }
}

extern "C" void kernel_launch(void* const* d_in, const int* in_sizes, int n_in,
                              void* d_out, int out_size, void* d_ws,
                              size_t ws_size, hipStream_t stream) {
  const float* x   = (const float*)d_in[0];
  const int*   ei  = (const int*)d_in[1];  // [2, E]: row0 = src, row1 = dst
  const float* W1n = (const float*)d_in[2];
  const float* W1s = (const float*)d_in[3];
  const float* b1  = (const float*)d_in[4];
  const float* W2n = (const float*)d_in[5];
  const float* W2s = (const float*)d_in[6];
  const float* b2  = (const float*)d_in[7];
  float* out = (float*)d_out;

  const int E = in_sizes[1] / 2;  // 1,600,000
  const int M = N_NODES;
  const int* src = ei;
  const int* dst = ei + E;
  const int NSB = (E + EPB - 1) / EPB;  // 196

  // Workspace layout (bytes):
  //   ep    @ 0           12,845,056  (NB*CAP u32; hnb8 aliases after bsort)
  //   ssrc  @ 12,845,056  12,845,056
  //   rows2 @ 25,690,112     802,816
  //   bcur  @ 26,492,928       3,136
  //   xnb8  @ 26,496,064   6,400,000  (fp8 M x 64)
  //   xsb   @ 32,896,064  12,800,000  (bf16 M x 64)
  //   hs    @ 45,696,064  12,800,000  (f32 M x 32)
  char* wsb = (char*)d_ws;
  unsigned*       ep    = (unsigned*)(wsb);
  int*            ssrc  = (int*)(wsb + 12845056);
  uint2*          rows2 = (uint2*)(wsb + 25690112);
  unsigned*       bcur  = (unsigned*)(wsb + 26492928);
  unsigned*       xnb8  = (unsigned*)(wsb + 26496064);
  unsigned short* xsb   = (unsigned short*)(wsb + 32896064);
  float*          hs    = (float*)(wsb + 45696064);
  unsigned*       hnb8  = (unsigned*)(wsb);  // aliases ep (dead after bsort)

  // 1) zero bucket cursors (3 KB)
  hipMemsetAsync(bcur, 0, NB * 4, stream);
  // 2) fusedA: 196-block 8-wave edge scatter + 128-row layer-1 dual-GEMM
  fusedA_k<<<NSB + GB2, 512, 0, stream>>>(src, dst, bcur, ep, x, W1n, W1s, b1,
                                          xnb8, xsb, E, NSB, M);
  // 3) per-bucket counting sort -> ssrc runs + rows2
  bsort_k<<<NB, 256, 0, stream>>>(ep, bcur, ssrc, rows2);
  // 4) fused gather1 + gemm2 (2-team split gather; 32 nodes/block)
  fgg_k<<<(M + FNB - 1) / FNB, 256, 0, stream>>>((const uint4*)xnb8, ssrc,
                                                 rows2, xsb, W2n, W2s, b2,
                                                 hnb8, hs, M);
  // 5) out = mean(fp8(hn)[src]) + hs (2-team split gather; 64 nodes/block)
  gather2_k<<<(M + 63) / 64, 256, 0, stream>>>((const uint4*)hnb8, ssrc,
                                               rows2, hs, out, M);
}